// Round 1
// baseline (525.061 us; speedup 1.0000x reference)
//
#include <hip/hip_runtime.h>

#define SS 2048
#define DD 1024
#define HH 16
#define HDIM 64
#define BB 2
#define FFD 4096
#define MR (BB*SS)   // 4096 rows

typedef __bf16 bf16;
typedef __bf16 bf16x4 __attribute__((ext_vector_type(4)));
typedef __bf16 bf16x8 __attribute__((ext_vector_type(8)));
typedef float f32x4 __attribute__((ext_vector_type(4)));

__device__ inline f32x4 mfma32(bf16x8 a, bf16x8 b, f32x4 c) {
  return __builtin_amdgcn_mfma_f32_16x16x32_bf16(a, b, c, 0, 0, 0);
}

__device__ inline void gload_lds16(const void* g, void* l) {
  __builtin_amdgcn_global_load_lds(
      (const __attribute__((address_space(1))) void*)g,
      (__attribute__((address_space(3))) void*)l, 16, 0, 0);
}

// ---------------- fp32 -> bf16 elementwise ----------------
__global__ __launch_bounds__(256)
void cvt_bf16_kernel(const float* __restrict__ in, bf16* __restrict__ out, int n) {
  int i = (blockIdx.x * 256 + threadIdx.x) * 4;
  if (i >= n) return;
  float4 v = *(const float4*)(in + i);
  bf16x4 o;
  o[0] = (bf16)v.x; o[1] = (bf16)v.y; o[2] = (bf16)v.z; o[3] = (bf16)v.w;
  *(bf16x4*)(out + i) = o;
}

// ---------------- W [K,N] fp32 -> Wt [N,K] bf16 ----------------
__global__ __launch_bounds__(256)
void transpose_w_kernel(const float* __restrict__ W, bf16* __restrict__ Wt,
                        int K, int N) {
  __shared__ float t[32][33];
  int tx = threadIdx.x & 31, ty = threadIdx.x >> 5;  // 32 x 8
  int n0 = blockIdx.x * 32, k0 = blockIdx.y * 32;
  #pragma unroll
  for (int i = 0; i < 4; ++i)
    t[ty + i*8][tx] = W[(size_t)(k0 + ty + i*8) * N + n0 + tx];
  __syncthreads();
  #pragma unroll
  for (int i = 0; i < 4; ++i)
    Wt[(size_t)(n0 + ty + i*8) * K + k0 + tx] = (bf16)t[tx][ty + i*8];
}

// ---------------- V2d [B*S, D] bf16 -> Vt [B,H,HD,S] bf16 ----------------
__global__ __launch_bounds__(256)
void transpose_v_kernel(const bf16* __restrict__ V2d, bf16* __restrict__ Vt) {
  __shared__ bf16 t[32][33];
  int tx = threadIdx.x & 31, ty = threadIdx.x >> 5;
  int s0 = blockIdx.x * 32, d0 = blockIdx.y * 32;
  int bh = blockIdx.z;
  int b = bh >> 4, h = bh & 15;
  #pragma unroll
  for (int i = 0; i < 4; ++i)
    t[ty + i*8][tx] = V2d[(size_t)(b*SS + s0 + ty + i*8) * DD + h*HDIM + d0 + tx];
  __syncthreads();
  #pragma unroll
  for (int i = 0; i < 4; ++i)
    Vt[((size_t)bh*HDIM + d0 + ty + i*8) * SS + s0 + tx] = t[tx][ty + i*8];
}

// ---------------- GEMM: C[M,N] = A[M,K] @ Bt[N,K]^T + bias ----------------
template<int OUT_BF16, int RELU>
__global__ __launch_bounds__(256)
void gemm_bt(const bf16* __restrict__ A, const bf16* __restrict__ Bt,
             const float* __restrict__ bias, void* __restrict__ Cout,
             int Mdim, int Ndim, int Kdim) {
  __shared__ bf16 As[128 * 32];
  __shared__ bf16 Bs[128 * 32];
  const int tid = threadIdx.x;
  const int wave = tid >> 6;
  const int lane = tid & 63;
  const int g = lane >> 4;
  const int r = lane & 15;
  const int m0 = blockIdx.y * 128;
  const int n0 = blockIdx.x * 128;
  const int wr = wave >> 1, wc = wave & 1;   // 2x2 waves -> 64x64 each
  f32x4 acc[4][4] = {};
  const int strow = tid >> 2;        // 0..63
  const int stcol = (tid & 3) * 8;
  const bf16* Abase = A + (size_t)(m0 + strow) * Kdim + stcol;
  const bf16* Bbase = Bt + (size_t)(n0 + strow) * Kdim + stcol;
  bf16* AsW = As + wave * 512;
  bf16* BsW = Bs + wave * 512;
  for (int k0 = 0; k0 < Kdim; k0 += 32) {
    __syncthreads();
    gload_lds16(Abase + k0, AsW);
    gload_lds16(Abase + k0 + (size_t)64 * Kdim, AsW + 2048);
    gload_lds16(Bbase + k0, BsW);
    gload_lds16(Bbase + k0 + (size_t)64 * Kdim, BsW + 2048);
    __syncthreads();
    bf16x8 af[4], bfr[4];
    #pragma unroll
    for (int i = 0; i < 4; ++i)
      af[i] = *(const bf16x8*)(As + (wr*64 + i*16 + r) * 32 + g * 8);
    #pragma unroll
    for (int i = 0; i < 4; ++i)
      bfr[i] = *(const bf16x8*)(Bs + (wc*64 + i*16 + r) * 32 + g * 8);
    #pragma unroll
    for (int mi = 0; mi < 4; ++mi)
      #pragma unroll
      for (int ni = 0; ni < 4; ++ni)
        acc[mi][ni] = mfma32(af[mi], bfr[ni], acc[mi][ni]);
  }
  #pragma unroll
  for (int mi = 0; mi < 4; ++mi) {
    #pragma unroll
    for (int ni = 0; ni < 4; ++ni) {
      const int col = n0 + wc*64 + ni*16 + r;
      const float bv = bias[col];
      #pragma unroll
      for (int j = 0; j < 4; ++j) {
        const int row = m0 + wr*64 + mi*16 + g*4 + j;
        float v = acc[mi][ni][j] + bv;
        if (RELU) v = fmaxf(v, 0.f);
        if (OUT_BF16) ((bf16*)Cout)[(size_t)row * Ndim + col] = (bf16)v;
        else          ((float*)Cout)[(size_t)row * Ndim + col] = v;
      }
    }
  }
}

// ---------------- flash attention: 1 wave = 16 q-rows of one (b,h) ----------------
__global__ __launch_bounds__(64)
void attn_kernel(const bf16* __restrict__ Q2d, const bf16* __restrict__ K2d,
                 const bf16* __restrict__ Vt, bf16* __restrict__ ctx) {
  const int lane = threadIdx.x;
  const int g = lane >> 4, r = lane & 15;
  const int qt = blockIdx.x;     // 0..127
  const int bh = blockIdx.y;     // 0..31
  const int b = bh >> 4, h = bh & 15;
  const int q0 = qt * 16;
  const bf16* qp = Q2d + (size_t)(b*SS + q0 + r) * DD + h * HDIM;
  bf16x8 qf0 = *(const bf16x8*)(qp + g * 8);
  bf16x8 qf1 = *(const bf16x8*)(qp + 32 + g * 8);
  f32x4 o[4] = {};
  float m = -3.0e38f, l = 0.f;
  const int qg = q0 + r;
  const int kend = q0 + 16;
  const int krp = 8 * (r >> 2) + (r & 3);   // permuted K row for S^T frag 1
  for (int k0 = 0; k0 < kend; k0 += 32) {
    const bf16* kp1 = K2d + (size_t)(b*SS + k0 + krp) * DD + h * HDIM;
    const bf16* kp2 = kp1 + (size_t)4 * DD;
    f32x4 c1 = {}, c2 = {};
    c1 = mfma32(*(const bf16x8*)(kp1 + g*8),      qf0, c1);
    c1 = mfma32(*(const bf16x8*)(kp1 + 32 + g*8), qf1, c1);
    c2 = mfma32(*(const bf16x8*)(kp2 + g*8),      qf0, c2);
    c2 = mfma32(*(const bf16x8*)(kp2 + 32 + g*8), qf1, c2);
    // lane holds S^T for q = q0+r, krows k0+8g+j (c1) and k0+8g+4+j (c2)
    float p1[4], p2[4];
    float tmax = -3.0e38f;
    const bool need_mask = (k0 + 31 > q0);
    #pragma unroll
    for (int j = 0; j < 4; ++j) {
      float s1 = c1[j] * 0.125f;
      float s2 = c2[j] * 0.125f;
      if (need_mask) {
        if (k0 + 8*g + j > qg)     s1 = -3.0e38f;
        if (k0 + 8*g + 4 + j > qg) s2 = -3.0e38f;
      }
      p1[j] = s1; p2[j] = s2;
      tmax = fmaxf(tmax, fmaxf(s1, s2));
    }
    tmax = fmaxf(tmax, __shfl_xor(tmax, 16));
    tmax = fmaxf(tmax, __shfl_xor(tmax, 32));
    const float mnew = fmaxf(m, tmax);
    const float sc = __expf(m - mnew);
    float tsum = 0.f;
    #pragma unroll
    for (int j = 0; j < 4; ++j) {
      p1[j] = __expf(p1[j] - mnew);
      p2[j] = __expf(p2[j] - mnew);
      tsum += p1[j] + p2[j];
    }
    tsum += __shfl_xor(tsum, 16);
    tsum += __shfl_xor(tsum, 32);
    l = l * sc + tsum;
    m = mnew;
    bf16x8 pf;
    #pragma unroll
    for (int j = 0; j < 4; ++j) { pf[j] = (bf16)p1[j]; pf[4 + j] = (bf16)p2[j]; }
    // rescale O (O rows are q-local = 4g+j; sc lives at lane q)
    #pragma unroll
    for (int j = 0; j < 4; ++j) {
      const float scj = __shfl(sc, 4*g + j);
      #pragma unroll
      for (int c = 0; c < 4; ++c) o[c][j] *= scj;
    }
    const bf16* vp = Vt + ((size_t)bh * HDIM + r) * SS + k0 + 8 * g;
    #pragma unroll
    for (int c = 0; c < 4; ++c) {
      bf16x8 vf = *(const bf16x8*)(vp + (size_t)c * 16 * SS);
      o[c] = mfma32(pf, vf, o[c]);
    }
  }
  #pragma unroll
  for (int j = 0; j < 4; ++j) {
    const float lj = __shfl(l, 4*g + j);
    const float inv = 1.f / lj;
    const int row = b*SS + q0 + 4*g + j;
    #pragma unroll
    for (int c = 0; c < 4; ++c)
      ctx[(size_t)row * DD + h*HDIM + c*16 + r] = (bf16)(o[c][j] * inv);
  }
}

// ---------------- LayerNorm(a + c) * g + b ----------------
__global__ __launch_bounds__(256)
void ln_kernel(const float* __restrict__ a, const float* __restrict__ c,
               const float* __restrict__ gam, const float* __restrict__ bet,
               float* __restrict__ outf, bf16* __restrict__ outb) {
  const int row = blockIdx.x;
  const int tid = threadIdx.x;
  const size_t base = (size_t)row * DD + tid * 4;
  float4 va = *(const float4*)(a + base);
  float4 vc = *(const float4*)(c + base);
  float x0 = va.x + vc.x, x1 = va.y + vc.y, x2 = va.z + vc.z, x3 = va.w + vc.w;
  float s  = x0 + x1 + x2 + x3;
  float s2 = x0*x0 + x1*x1 + x2*x2 + x3*x3;
  #pragma unroll
  for (int off = 32; off > 0; off >>= 1) {
    s  += __shfl_xor(s,  off);
    s2 += __shfl_xor(s2, off);
  }
  __shared__ float red[8];
  const int wv = tid >> 6;
  if ((tid & 63) == 0) { red[wv] = s; red[wv + 4] = s2; }
  __syncthreads();
  s  = red[0] + red[1] + red[2] + red[3];
  s2 = red[4] + red[5] + red[6] + red[7];
  const float mu  = s * (1.f / DD);
  const float var = s2 * (1.f / DD) - mu * mu;
  const float rs  = rsqrtf(var + 1e-5f);
  float4 vg = *(const float4*)(gam + tid * 4);
  float4 vb = *(const float4*)(bet + tid * 4);
  float y0 = (x0 - mu) * rs * vg.x + vb.x;
  float y1 = (x1 - mu) * rs * vg.y + vb.y;
  float y2 = (x2 - mu) * rs * vg.z + vb.z;
  float y3 = (x3 - mu) * rs * vg.w + vb.w;
  float4 yo; yo.x = y0; yo.y = y1; yo.z = y2; yo.w = y3;
  *(float4*)(outf + base) = yo;
  if (outb) {
    bf16x4 ob;
    ob[0] = (bf16)y0; ob[1] = (bf16)y1; ob[2] = (bf16)y2; ob[3] = (bf16)y3;
    *(bf16x4*)(outb + base) = ob;
  }
}

extern "C" void kernel_launch(void* const* d_in, const int* in_sizes, int n_in,
                              void* d_out, int out_size, void* d_ws, size_t ws_size,
                              hipStream_t stream) {
  const float* src  = (const float*)d_in[0];
  const float* Wq   = (const float*)d_in[2];
  const float* bq   = (const float*)d_in[3];
  const float* Wk   = (const float*)d_in[4];
  const float* bk   = (const float*)d_in[5];
  const float* Wv   = (const float*)d_in[6];
  const float* bv   = (const float*)d_in[7];
  const float* Wo   = (const float*)d_in[8];
  const float* bo   = (const float*)d_in[9];
  const float* W1   = (const float*)d_in[10];
  const float* b1   = (const float*)d_in[11];
  const float* W2   = (const float*)d_in[12];
  const float* b2   = (const float*)d_in[13];
  const float* ln1g = (const float*)d_in[14];
  const float* ln1b = (const float*)d_in[15];
  const float* ln2g = (const float*)d_in[16];
  const float* ln2b = (const float*)d_in[17];

  char* ws = (char*)d_ws;
  const size_t MB = 1024 * 1024;
  bf16* wqt  = (bf16*)(ws + 0 * MB);
  bf16* wkt  = (bf16*)(ws + 2 * MB);
  bf16* wvt  = (bf16*)(ws + 4 * MB);
  bf16* wot  = (bf16*)(ws + 6 * MB);
  bf16* w1t  = (bf16*)(ws + 8 * MB);    // [FFD, DD]
  bf16* w2t  = (bf16*)(ws + 16 * MB);   // [DD, FFD]
  bf16* bsrc = (bf16*)(ws + 24 * MB);   // later reused as xb
  bf16* xb   = bsrc;
  bf16* q2d  = (bf16*)(ws + 32 * MB);
  bf16* k2d  = (bf16*)(ws + 40 * MB);
  bf16* v2d  = (bf16*)(ws + 48 * MB);
  bf16* vt   = (bf16*)(ws + 56 * MB);
  bf16* ff1  = (bf16*)(ws + 32 * MB);   // reuse q2d..vt after attention
  bf16* ctx  = (bf16*)(ws + 64 * MB);
  float* attn_out = (float*)(ws + 72 * MB);
  float* ff2 = attn_out;                // reuse after LN1
  float* xf  = (float*)(ws + 88 * MB);
  float* outp = (float*)d_out;

  // conversions
  cvt_bf16_kernel<<<(MR * DD) / 1024, 256, 0, stream>>>(src, bsrc, MR * DD);
  transpose_w_kernel<<<dim3(32, 32), 256, 0, stream>>>(Wq, wqt, DD, DD);
  transpose_w_kernel<<<dim3(32, 32), 256, 0, stream>>>(Wk, wkt, DD, DD);
  transpose_w_kernel<<<dim3(32, 32), 256, 0, stream>>>(Wv, wvt, DD, DD);
  transpose_w_kernel<<<dim3(32, 32), 256, 0, stream>>>(Wo, wot, DD, DD);
  transpose_w_kernel<<<dim3(128, 32), 256, 0, stream>>>(W1, w1t, DD, FFD);
  transpose_w_kernel<<<dim3(32, 128), 256, 0, stream>>>(W2, w2t, FFD, DD);

  // QKV projections
  gemm_bt<1, 0><<<dim3(8, 32), 256, 0, stream>>>(bsrc, wqt, bq, q2d, MR, DD, DD);
  gemm_bt<1, 0><<<dim3(8, 32), 256, 0, stream>>>(bsrc, wkt, bk, k2d, MR, DD, DD);
  gemm_bt<1, 0><<<dim3(8, 32), 256, 0, stream>>>(bsrc, wvt, bv, v2d, MR, DD, DD);
  transpose_v_kernel<<<dim3(SS / 32, HDIM / 32, BB * HH), 256, 0, stream>>>(v2d, vt);

  // attention
  attn_kernel<<<dim3(SS / 16, BB * HH), 64, 0, stream>>>(q2d, k2d, vt, ctx);

  // output projection + LN1
  gemm_bt<0, 0><<<dim3(8, 32), 256, 0, stream>>>(ctx, wot, bo, attn_out, MR, DD, DD);
  ln_kernel<<<MR, 256, 0, stream>>>(src, attn_out, ln1g, ln1b, xf, xb);

  // FFN + LN2
  gemm_bt<1, 1><<<dim3(32, 32), 256, 0, stream>>>(xb, w1t, b1, ff1, MR, FFD, DD);
  gemm_bt<0, 0><<<dim3(8, 32), 256, 0, stream>>>(ff1, w2t, b2, ff2, MR, DD, FFD);
  ln_kernel<<<MR, 256, 0, stream>>>(xf, ff2, ln2g, ln2b, outp, (bf16*)nullptr);
}

// Round 2
// 489.737 us; speedup vs baseline: 1.0721x; 1.0721x over previous
//
#include <hip/hip_runtime.h>

#define SS 2048
#define DD 1024
#define HH 16
#define HDIM 64
#define BB 2
#define FFD 4096
#define MR (BB*SS)   // 4096 rows
#define QKVLD 3072   // fused qkv row stride

typedef __bf16 bf16;
typedef __bf16 bf16x4 __attribute__((ext_vector_type(4)));
typedef __bf16 bf16x8 __attribute__((ext_vector_type(8)));
typedef float f32x4 __attribute__((ext_vector_type(4)));

__device__ inline f32x4 mfma32(bf16x8 a, bf16x8 b, f32x4 c) {
  return __builtin_amdgcn_mfma_f32_16x16x32_bf16(a, b, c, 0, 0, 0);
}

__device__ inline void gload_lds16(const void* g, void* l) {
  __builtin_amdgcn_global_load_lds(
      (const __attribute__((address_space(1))) void*)g,
      (__attribute__((address_space(3))) void*)l, 16, 0, 0);
}

// ---------------- fp32 -> bf16 elementwise ----------------
__global__ __launch_bounds__(256)
void cvt_bf16_kernel(const float* __restrict__ in, bf16* __restrict__ out, int n) {
  int i = (blockIdx.x * 256 + threadIdx.x) * 4;
  if (i >= n) return;
  float4 v = *(const float4*)(in + i);
  bf16x4 o;
  o[0] = (bf16)v.x; o[1] = (bf16)v.y; o[2] = (bf16)v.z; o[3] = (bf16)v.w;
  *(bf16x4*)(out + i) = o;
}

// ---------------- concat bias qkv ----------------
__global__ __launch_bounds__(256)
void concat_bias_kernel(const float* __restrict__ bq, const float* __restrict__ bk,
                        const float* __restrict__ bv, float* __restrict__ out) {
  int i = blockIdx.x * 256 + threadIdx.x;
  out[i] = i < 1024 ? bq[i] : (i < 2048 ? bk[i - 1024] : bv[i - 2048]);
}

// ---------------- W [K,N] fp32 -> Wt [N,K] bf16 ----------------
__global__ __launch_bounds__(256)
void transpose_w_kernel(const float* __restrict__ W, bf16* __restrict__ Wt,
                        int K, int N) {
  __shared__ float t[32][33];
  int tx = threadIdx.x & 31, ty = threadIdx.x >> 5;  // 32 x 8
  int n0 = blockIdx.x * 32, k0 = blockIdx.y * 32;
  #pragma unroll
  for (int i = 0; i < 4; ++i)
    t[ty + i*8][tx] = W[(size_t)(k0 + ty + i*8) * N + n0 + tx];
  __syncthreads();
  #pragma unroll
  for (int i = 0; i < 4; ++i)
    Wt[(size_t)(n0 + ty + i*8) * K + k0 + tx] = (bf16)t[tx][ty + i*8];
}

// ---------------- V (cols of qkv2d) -> Vt [B,H,HD,S] bf16 ----------------
__global__ __launch_bounds__(256)
void transpose_v_kernel(const bf16* __restrict__ V2d, bf16* __restrict__ Vt) {
  __shared__ bf16 t[32][33];
  int tx = threadIdx.x & 31, ty = threadIdx.x >> 5;
  int s0 = blockIdx.x * 32, d0 = blockIdx.y * 32;
  int bh = blockIdx.z;
  int b = bh >> 4, h = bh & 15;
  #pragma unroll
  for (int i = 0; i < 4; ++i)
    t[ty + i*8][tx] = V2d[(size_t)(b*SS + s0 + ty + i*8) * QKVLD + h*HDIM + d0 + tx];
  __syncthreads();
  #pragma unroll
  for (int i = 0; i < 4; ++i)
    Vt[((size_t)bh*HDIM + d0 + ty + i*8) * SS + s0 + tx] = t[tx][ty + i*8];
}

// ---------------- GEMM: C[M,N] = A[M,K] @ Bt[N,K]^T + bias ----------------
template<int OUT_BF16, int RELU>
__global__ __launch_bounds__(256)
void gemm_bt(const bf16* __restrict__ A, const bf16* __restrict__ Bt,
             const float* __restrict__ bias, void* __restrict__ Cout,
             int Mdim, int Ndim, int Kdim) {
  __shared__ bf16 As[128 * 32];
  __shared__ bf16 Bs[128 * 32];
  const int tid = threadIdx.x;
  const int wave = tid >> 6;
  const int lane = tid & 63;
  const int g = lane >> 4;
  const int r = lane & 15;
  const int m0 = blockIdx.y * 128;
  const int n0 = blockIdx.x * 128;
  const int wr = wave >> 1, wc = wave & 1;   // 2x2 waves -> 64x64 each
  f32x4 acc[4][4] = {};
  const int strow = tid >> 2;        // 0..63
  const int stcol = (tid & 3) * 8;
  const bf16* Abase = A + (size_t)(m0 + strow) * Kdim + stcol;
  const bf16* Bbase = Bt + (size_t)(n0 + strow) * Kdim + stcol;
  bf16* AsW = As + wave * 512;
  bf16* BsW = Bs + wave * 512;
  for (int k0 = 0; k0 < Kdim; k0 += 32) {
    __syncthreads();
    gload_lds16(Abase + k0, AsW);
    gload_lds16(Abase + k0 + (size_t)64 * Kdim, AsW + 2048);
    gload_lds16(Bbase + k0, BsW);
    gload_lds16(Bbase + k0 + (size_t)64 * Kdim, BsW + 2048);
    __syncthreads();
    bf16x8 af[4], bfr[4];
    #pragma unroll
    for (int i = 0; i < 4; ++i)
      af[i] = *(const bf16x8*)(As + (wr*64 + i*16 + r) * 32 + g * 8);
    #pragma unroll
    for (int i = 0; i < 4; ++i)
      bfr[i] = *(const bf16x8*)(Bs + (wc*64 + i*16 + r) * 32 + g * 8);
    #pragma unroll
    for (int mi = 0; mi < 4; ++mi)
      #pragma unroll
      for (int ni = 0; ni < 4; ++ni)
        acc[mi][ni] = mfma32(af[mi], bfr[ni], acc[mi][ni]);
  }
  #pragma unroll
  for (int mi = 0; mi < 4; ++mi) {
    #pragma unroll
    for (int ni = 0; ni < 4; ++ni) {
      const int col = n0 + wc*64 + ni*16 + r;
      const float bv = bias[col];
      #pragma unroll
      for (int j = 0; j < 4; ++j) {
        const int row = m0 + wr*64 + mi*16 + g*4 + j;
        float v = acc[mi][ni][j] + bv;
        if (RELU) v = fmaxf(v, 0.f);
        if (OUT_BF16) ((bf16*)Cout)[(size_t)row * Ndim + col] = (bf16)v;
        else          ((float*)Cout)[(size_t)row * Ndim + col] = v;
      }
    }
  }
}

// ---------------- flash attention v2: 4 waves/block, 64-wide k-steps ----------------
// block = 256 threads; wave w owns q-rows [qblk*64 + 16w, +16). Q/K read from
// fused qkv2d (row stride QKVLD). Blocks issued in reverse for load balance.
__global__ __launch_bounds__(256)
void attn_kernel(const bf16* __restrict__ Q2d, const bf16* __restrict__ K2d,
                 const bf16* __restrict__ Vt, bf16* __restrict__ ctx) {
  const int tid = threadIdx.x;
  const int wave = tid >> 6;
  const int lane = tid & 63;
  const int g = lane >> 4, r = lane & 15;
  const int qblk = gridDim.x - 1 - blockIdx.x;   // long tails first
  const int bh = blockIdx.y;                     // 0..31
  const int b = bh >> 4, h = bh & 15;
  const int q0 = qblk * 64 + wave * 16;
  const bf16* qp = Q2d + (size_t)(b*SS + q0 + r) * QKVLD + h * HDIM;
  bf16x8 qf0 = *(const bf16x8*)(qp + g * 8);
  bf16x8 qf1 = *(const bf16x8*)(qp + 32 + g * 8);
  f32x4 o[4] = {};
  float m = -3.0e38f, l = 0.f;
  const int qg = q0 + r;
  const int kend = q0 + 16;
  const int krp = 8 * (r >> 2) + (r & 3);   // permuted K row for S^T frag
  for (int k0 = 0; k0 < kend; k0 += 64) {
    const bf16* kp = K2d + (size_t)(b*SS + k0 + krp) * QKVLD + h * HDIM;
    // sub-blocks of 16 k-rows: +0, +4, +32, +36 (permuted row sets)
    f32x4 c0 = {}, c1 = {}, c2 = {}, c3 = {};
    {
      const bf16* kp0 = kp;
      const bf16* kp1 = kp + (size_t)4  * QKVLD;
      const bf16* kp2 = kp + (size_t)32 * QKVLD;
      const bf16* kp3 = kp + (size_t)36 * QKVLD;
      c0 = mfma32(*(const bf16x8*)(kp0 + g*8),      qf0, c0);
      c1 = mfma32(*(const bf16x8*)(kp1 + g*8),      qf0, c1);
      c2 = mfma32(*(const bf16x8*)(kp2 + g*8),      qf0, c2);
      c3 = mfma32(*(const bf16x8*)(kp3 + g*8),      qf0, c3);
      c0 = mfma32(*(const bf16x8*)(kp0 + 32 + g*8), qf1, c0);
      c1 = mfma32(*(const bf16x8*)(kp1 + 32 + g*8), qf1, c1);
      c2 = mfma32(*(const bf16x8*)(kp2 + 32 + g*8), qf1, c2);
      c3 = mfma32(*(const bf16x8*)(kp3 + 32 + g*8), qf1, c3);
    }
    // lane holds S^T: c0[j] -> k0+8g+j, c1[j] -> k0+8g+4+j,
    //                 c2[j] -> k0+32+8g+j, c3[j] -> k0+32+8g+4+j, all q=q0+r
    float p0[4], p1[4], p2[4], p3[4];
    float tmax = -3.0e38f;
    const bool need_mask = (k0 + 63 > qg);
    #pragma unroll
    for (int j = 0; j < 4; ++j) {
      float s0 = c0[j] * 0.125f;
      float s1 = c1[j] * 0.125f;
      float s2 = c2[j] * 0.125f;
      float s3 = c3[j] * 0.125f;
      if (need_mask) {
        if (k0 + 8*g + j > qg)          s0 = -3.0e38f;
        if (k0 + 8*g + 4 + j > qg)      s1 = -3.0e38f;
        if (k0 + 32 + 8*g + j > qg)     s2 = -3.0e38f;
        if (k0 + 32 + 8*g + 4 + j > qg) s3 = -3.0e38f;
      }
      p0[j] = s0; p1[j] = s1; p2[j] = s2; p3[j] = s3;
      tmax = fmaxf(tmax, fmaxf(fmaxf(s0, s1), fmaxf(s2, s3)));
    }
    tmax = fmaxf(tmax, __shfl_xor(tmax, 16));
    tmax = fmaxf(tmax, __shfl_xor(tmax, 32));
    const float mnew = fmaxf(m, tmax);
    const float sc = __expf(m - mnew);
    float tsum = 0.f;
    #pragma unroll
    for (int j = 0; j < 4; ++j) {
      p0[j] = __expf(p0[j] - mnew);
      p1[j] = __expf(p1[j] - mnew);
      p2[j] = __expf(p2[j] - mnew);
      p3[j] = __expf(p3[j] - mnew);
      tsum += (p0[j] + p1[j]) + (p2[j] + p3[j]);
    }
    tsum += __shfl_xor(tsum, 16);
    tsum += __shfl_xor(tsum, 32);
    l = l * sc + tsum;
    m = mnew;
    bf16x8 pfa, pfb;
    #pragma unroll
    for (int j = 0; j < 4; ++j) {
      pfa[j] = (bf16)p0[j]; pfa[4 + j] = (bf16)p1[j];
      pfb[j] = (bf16)p2[j]; pfb[4 + j] = (bf16)p3[j];
    }
    // rescale O (O rows are q-local = 4g+j; sc lives at lane q=r)
    #pragma unroll
    for (int j = 0; j < 4; ++j) {
      const float scj = __shfl(sc, 4*g + j);
      #pragma unroll
      for (int c = 0; c < 4; ++c) o[c][j] *= scj;
    }
    const bf16* vp = Vt + ((size_t)bh * HDIM + r) * SS + k0 + 8 * g;
    #pragma unroll
    for (int c = 0; c < 4; ++c) {
      bf16x8 vfa = *(const bf16x8*)(vp + (size_t)c * 16 * SS);
      bf16x8 vfb = *(const bf16x8*)(vp + 32 + (size_t)c * 16 * SS);
      o[c] = mfma32(pfa, vfa, o[c]);
      o[c] = mfma32(pfb, vfb, o[c]);
    }
  }
  #pragma unroll
  for (int j = 0; j < 4; ++j) {
    const float lj = __shfl(l, 4*g + j);
    const float inv = 1.f / lj;
    const int row = b*SS + q0 + 4*g + j;
    #pragma unroll
    for (int c = 0; c < 4; ++c)
      ctx[(size_t)row * DD + h*HDIM + c*16 + r] = (bf16)(o[c][j] * inv);
  }
}

// ---------------- LayerNorm(a + c) * g + b ----------------
__global__ __launch_bounds__(256)
void ln_kernel(const float* __restrict__ a, const float* __restrict__ c,
               const float* __restrict__ gam, const float* __restrict__ bet,
               float* __restrict__ outf, bf16* __restrict__ outb) {
  const int row = blockIdx.x;
  const int tid = threadIdx.x;
  const size_t base = (size_t)row * DD + tid * 4;
  float4 va = *(const float4*)(a + base);
  float4 vc = *(const float4*)(c + base);
  float x0 = va.x + vc.x, x1 = va.y + vc.y, x2 = va.z + vc.z, x3 = va.w + vc.w;
  float s  = x0 + x1 + x2 + x3;
  float s2 = x0*x0 + x1*x1 + x2*x2 + x3*x3;
  #pragma unroll
  for (int off = 32; off > 0; off >>= 1) {
    s  += __shfl_xor(s,  off);
    s2 += __shfl_xor(s2, off);
  }
  __shared__ float red[8];
  const int wv = tid >> 6;
  if ((tid & 63) == 0) { red[wv] = s; red[wv + 4] = s2; }
  __syncthreads();
  s  = red[0] + red[1] + red[2] + red[3];
  s2 = red[4] + red[5] + red[6] + red[7];
  const float mu  = s * (1.f / DD);
  const float var = s2 * (1.f / DD) - mu * mu;
  const float rs  = rsqrtf(var + 1e-5f);
  float4 vg = *(const float4*)(gam + tid * 4);
  float4 vb = *(const float4*)(bet + tid * 4);
  float y0 = (x0 - mu) * rs * vg.x + vb.x;
  float y1 = (x1 - mu) * rs * vg.y + vb.y;
  float y2 = (x2 - mu) * rs * vg.z + vb.z;
  float y3 = (x3 - mu) * rs * vg.w + vb.w;
  float4 yo; yo.x = y0; yo.y = y1; yo.z = y2; yo.w = y3;
  *(float4*)(outf + base) = yo;
  if (outb) {
    bf16x4 ob;
    ob[0] = (bf16)y0; ob[1] = (bf16)y1; ob[2] = (bf16)y2; ob[3] = (bf16)y3;
    *(bf16x4*)(outb + base) = ob;
  }
}

extern "C" void kernel_launch(void* const* d_in, const int* in_sizes, int n_in,
                              void* d_out, int out_size, void* d_ws, size_t ws_size,
                              hipStream_t stream) {
  const float* src  = (const float*)d_in[0];
  const float* Wq   = (const float*)d_in[2];
  const float* bq   = (const float*)d_in[3];
  const float* Wk   = (const float*)d_in[4];
  const float* bk   = (const float*)d_in[5];
  const float* Wv   = (const float*)d_in[6];
  const float* bv   = (const float*)d_in[7];
  const float* Wo   = (const float*)d_in[8];
  const float* bo   = (const float*)d_in[9];
  const float* W1   = (const float*)d_in[10];
  const float* b1   = (const float*)d_in[11];
  const float* W2   = (const float*)d_in[12];
  const float* b2   = (const float*)d_in[13];
  const float* ln1g = (const float*)d_in[14];
  const float* ln1b = (const float*)d_in[15];
  const float* ln2g = (const float*)d_in[16];
  const float* ln2b = (const float*)d_in[17];

  char* ws = (char*)d_ws;
  const size_t MB = 1024 * 1024;
  bf16* wqkvt = (bf16*)(ws + 0 * MB);    // [3072][1024] bf16 = 6MB
  bf16* wot   = (bf16*)(ws + 6 * MB);    // 2MB
  bf16* w1t   = (bf16*)(ws + 8 * MB);    // [FFD][DD] = 8MB
  bf16* w2t   = (bf16*)(ws + 16 * MB);   // [DD][FFD] = 8MB
  bf16* bsrc  = (bf16*)(ws + 24 * MB);   // 8MB; reused as xb
  bf16* xb    = bsrc;
  bf16* qkv   = (bf16*)(ws + 32 * MB);   // [4096][3072] = 24MB
  bf16* vt    = (bf16*)(ws + 56 * MB);   // [32][64][2048] = 8MB
  bf16* ctx   = (bf16*)(ws + 64 * MB);   // 8MB
  bf16* ff1   = qkv;                     // [4096][4096] = 32MB, reuses qkv+vt
  float* xf   = (float*)(ws + 72 * MB);  // 16MB
  float* bqkv = (float*)(ws + 88 * MB);  // 12KB
  float* attn_out = (float*)d_out;       // fp32 scratch in d_out (overwritten by LN2)
  float* ff2  = (float*)d_out;
  float* outp = (float*)d_out;

  // conversions
  cvt_bf16_kernel<<<(MR * DD) / 1024, 256, 0, stream>>>(src, bsrc, MR * DD);
  transpose_w_kernel<<<dim3(32, 32), 256, 0, stream>>>(Wq, wqkvt,            DD, DD);
  transpose_w_kernel<<<dim3(32, 32), 256, 0, stream>>>(Wk, wqkvt + 1024*1024, DD, DD);
  transpose_w_kernel<<<dim3(32, 32), 256, 0, stream>>>(Wv, wqkvt + 2048*1024, DD, DD);
  transpose_w_kernel<<<dim3(32, 32), 256, 0, stream>>>(Wo, wot, DD, DD);
  transpose_w_kernel<<<dim3(128, 32), 256, 0, stream>>>(W1, w1t, DD, FFD);
  transpose_w_kernel<<<dim3(32, 128), 256, 0, stream>>>(W2, w2t, FFD, DD);
  concat_bias_kernel<<<12, 256, 0, stream>>>(bq, bk, bv, bqkv);

  // fused QKV projection: [4096,1024] @ [1024,3072] -> [4096,3072]
  gemm_bt<1, 0><<<dim3(24, 32), 256, 0, stream>>>(bsrc, wqkvt, bqkv, qkv, MR, QKVLD, DD);
  transpose_v_kernel<<<dim3(SS / 32, HDIM / 32, BB * HH), 256, 0, stream>>>(qkv + 2048, vt);

  // attention (Q at col 0, K at col 1024 of qkv)
  attn_kernel<<<dim3(SS / 64, BB * HH), 256, 0, stream>>>(qkv, qkv + 1024, vt, ctx);

  // output projection + LN1
  gemm_bt<0, 0><<<dim3(8, 32), 256, 0, stream>>>(ctx, wot, bo, attn_out, MR, DD, DD);
  ln_kernel<<<MR, 256, 0, stream>>>(src, attn_out, ln1g, ln1b, xf, xb);

  // FFN + LN2
  gemm_bt<1, 1><<<dim3(32, 32), 256, 0, stream>>>(xb, w1t, b1, ff1, MR, FFD, DD);
  gemm_bt<0, 0><<<dim3(8, 32), 256, 0, stream>>>(ff1, w2t, b2, ff2, MR, DD, FFD);
  ln_kernel<<<MR, 256, 0, stream>>>(xf, ff2, ln2g, ln2b, outp, (bf16*)nullptr);
}

// Round 3
// 316.633 us; speedup vs baseline: 1.6583x; 1.5467x over previous
//
#include <hip/hip_runtime.h>

#define SS 2048
#define DD 1024
#define HH 16
#define HDIM 64
#define BB 2
#define FFD 4096
#define MR (BB*SS)   // 4096 rows
#define QKVLD 3072   // fused qkv row stride

typedef __bf16 bf16;
typedef __bf16 bf16x4 __attribute__((ext_vector_type(4)));
typedef __bf16 bf16x8 __attribute__((ext_vector_type(8)));
typedef float f32x4 __attribute__((ext_vector_type(4)));

__device__ inline f32x4 mfma32(bf16x8 a, bf16x8 b, f32x4 c) {
  return __builtin_amdgcn_mfma_f32_16x16x32_bf16(a, b, c, 0, 0, 0);
}

__device__ inline void gload_lds16(const void* g, void* l) {
  __builtin_amdgcn_global_load_lds(
      (const __attribute__((address_space(1))) void*)g,
      (__attribute__((address_space(3))) void*)l, 16, 0, 0);
}

// ---------------- fp32 -> bf16 elementwise ----------------
__global__ __launch_bounds__(256)
void cvt_bf16_kernel(const float* __restrict__ in, bf16* __restrict__ out, int n) {
  int i = (blockIdx.x * 256 + threadIdx.x) * 4;
  if (i >= n) return;
  float4 v = *(const float4*)(in + i);
  bf16x4 o;
  o[0] = (bf16)v.x; o[1] = (bf16)v.y; o[2] = (bf16)v.z; o[3] = (bf16)v.w;
  *(bf16x4*)(out + i) = o;
}

// ---------------- concat bias qkv ----------------
__global__ __launch_bounds__(256)
void concat_bias_kernel(const float* __restrict__ bq, const float* __restrict__ bk,
                        const float* __restrict__ bv, float* __restrict__ out) {
  int i = blockIdx.x * 256 + threadIdx.x;
  out[i] = i < 1024 ? bq[i] : (i < 2048 ? bk[i - 1024] : bv[i - 2048]);
}

// ---------------- W [K,N] fp32 -> Wt [N,K] bf16 ----------------
__global__ __launch_bounds__(256)
void transpose_w_kernel(const float* __restrict__ W, bf16* __restrict__ Wt,
                        int K, int N) {
  __shared__ float t[32][33];
  int tx = threadIdx.x & 31, ty = threadIdx.x >> 5;  // 32 x 8
  int n0 = blockIdx.x * 32, k0 = blockIdx.y * 32;
  #pragma unroll
  for (int i = 0; i < 4; ++i)
    t[ty + i*8][tx] = W[(size_t)(k0 + ty + i*8) * N + n0 + tx];
  __syncthreads();
  #pragma unroll
  for (int i = 0; i < 4; ++i)
    Wt[(size_t)(n0 + ty + i*8) * K + k0 + tx] = (bf16)t[tx][ty + i*8];
}

// ---------------- V (cols of qkv2d) -> Vt [B,H,HD,S] bf16 ----------------
__global__ __launch_bounds__(256)
void transpose_v_kernel(const bf16* __restrict__ V2d, bf16* __restrict__ Vt) {
  __shared__ bf16 t[32][33];
  int tx = threadIdx.x & 31, ty = threadIdx.x >> 5;
  int s0 = blockIdx.x * 32, d0 = blockIdx.y * 32;
  int bh = blockIdx.z;
  int b = bh >> 4, h = bh & 15;
  #pragma unroll
  for (int i = 0; i < 4; ++i)
    t[ty + i*8][tx] = V2d[(size_t)(b*SS + s0 + ty + i*8) * QKVLD + h*HDIM + d0 + tx];
  __syncthreads();
  #pragma unroll
  for (int i = 0; i < 4; ++i)
    Vt[((size_t)bh*HDIM + d0 + ty + i*8) * SS + s0 + tx] = t[tx][ty + i*8];
}

// ---------------- GEMM: C[M,N] = A[M,K] @ Bt[N,K]^T + bias ----------------
template<int OUT_BF16, int RELU>
__global__ __launch_bounds__(256)
void gemm_bt(const bf16* __restrict__ A, const bf16* __restrict__ Bt,
             const float* __restrict__ bias, void* __restrict__ Cout,
             int Mdim, int Ndim, int Kdim) {
  __shared__ bf16 As[128 * 32];
  __shared__ bf16 Bs[128 * 32];
  const int tid = threadIdx.x;
  const int wave = tid >> 6;
  const int lane = tid & 63;
  const int g = lane >> 4;
  const int r = lane & 15;
  const int m0 = blockIdx.y * 128;
  const int n0 = blockIdx.x * 128;
  const int wr = wave >> 1, wc = wave & 1;   // 2x2 waves -> 64x64 each
  f32x4 acc[4][4] = {};
  const int strow = tid >> 2;        // 0..63
  const int stcol = (tid & 3) * 8;
  const bf16* Abase = A + (size_t)(m0 + strow) * Kdim + stcol;
  const bf16* Bbase = Bt + (size_t)(n0 + strow) * Kdim + stcol;
  bf16* AsW = As + wave * 512;
  bf16* BsW = Bs + wave * 512;
  for (int k0 = 0; k0 < Kdim; k0 += 32) {
    __syncthreads();
    gload_lds16(Abase + k0, AsW);
    gload_lds16(Abase + k0 + (size_t)64 * Kdim, AsW + 2048);
    gload_lds16(Bbase + k0, BsW);
    gload_lds16(Bbase + k0 + (size_t)64 * Kdim, BsW + 2048);
    __syncthreads();
    bf16x8 af[4], bfr[4];
    #pragma unroll
    for (int i = 0; i < 4; ++i)
      af[i] = *(const bf16x8*)(As + (wr*64 + i*16 + r) * 32 + g * 8);
    #pragma unroll
    for (int i = 0; i < 4; ++i)
      bfr[i] = *(const bf16x8*)(Bs + (wc*64 + i*16 + r) * 32 + g * 8);
    #pragma unroll
    for (int mi = 0; mi < 4; ++mi)
      #pragma unroll
      for (int ni = 0; ni < 4; ++ni)
        acc[mi][ni] = mfma32(af[mi], bfr[ni], acc[mi][ni]);
  }
  #pragma unroll
  for (int mi = 0; mi < 4; ++mi) {
    #pragma unroll
    for (int ni = 0; ni < 4; ++ni) {
      const int col = n0 + wc*64 + ni*16 + r;
      const float bv = bias[col];
      #pragma unroll
      for (int j = 0; j < 4; ++j) {
        const int row = m0 + wr*64 + mi*16 + g*4 + j;
        float v = acc[mi][ni][j] + bv;
        if (RELU) v = fmaxf(v, 0.f);
        if (OUT_BF16) ((bf16*)Cout)[(size_t)row * Ndim + col] = (bf16)v;
        else          ((float*)Cout)[(size_t)row * Ndim + col] = v;
      }
    }
  }
}

// ---------------- flash attention v3: LDS-staged K/V, double-buffered ----------------
// Block = 256 threads (4 waves). Each block processes TWO 64-row q-tiles
// {p, 31-p} (uniform work). Per k-step (64 kv rows): K and V tiles staged
// cooperatively into LDS via global_load_lds (coalesced), layout
// [half][64 rows][32 elems] (64B LDS rows = m97 geometry). Stage of step t+1
// issued before compute of step t; __syncthreads() (implicit vmcnt(0) drain)
// closes each step.
__global__ __launch_bounds__(256)
void attn_kernel(const bf16* __restrict__ Q2d, const bf16* __restrict__ K2d,
                 const bf16* __restrict__ Vt, bf16* __restrict__ ctx) {
  __shared__ bf16 Ks[2 * 4096];   // 2 bufs x [2 halves][64][32]
  __shared__ bf16 Vs[2 * 4096];
  const int tid = threadIdx.x;
  const int wave = tid >> 6;
  const int lane = tid & 63;
  const int g = lane >> 4, r = lane & 15;
  const int p = blockIdx.x;          // 0..15 (pair index)
  const int bh = blockIdx.y;         // 0..31
  const int b = bh >> 4, h = bh & 15;

  // staging lane geometry: round covers one 64x32 half; row = wave*16+lane/4
  const int strow = wave * 16 + (lane >> 2);   // 0..63
  const int stcol = (lane & 3) * 8;            // 0,8,16,24
  const bf16* srcK0 = K2d + (size_t)(b*SS + strow) * QKVLD + h*HDIM + stcol;
  const bf16* srcK1 = srcK0 + 32;
  const bf16* srcV0 = Vt + ((size_t)bh*HDIM + strow) * SS + stcol;
  const bf16* srcV1 = srcV0 + 32;

  // fragment LDS offsets (elements), loop-invariant
  const int kr0 = 8 * (r >> 2) + (r & 3);      // permuted K row for S^T frag
  const int oKa0 = (kr0     ) * 32 + g * 8, oKb0 = 2048 + oKa0;
  const int oKa1 = (kr0 +  4) * 32 + g * 8, oKb1 = 2048 + oKa1;
  const int oKa2 = (kr0 + 32) * 32 + g * 8, oKb2 = 2048 + oKa2;
  const int oKa3 = (kr0 + 36) * 32 + g * 8, oKb3 = 2048 + oKa3;

  #pragma unroll
  for (int tt = 0; tt < 2; ++tt) {
    const int tile = tt ? (31 - p) : p;
    const int q0 = tile * 64 + wave * 16;
    const int qg = q0 + r;
    const bf16* qp = Q2d + (size_t)(b*SS + q0 + r) * QKVLD + h * HDIM;
    const bf16x8 qf0 = *(const bf16x8*)(qp + g * 8);
    const bf16x8 qf1 = *(const bf16x8*)(qp + 32 + g * 8);
    f32x4 ov[4] = {};
    float m = -3.0e38f, l = 0.f;
    const int nst = tile + 1;
    // prologue stage (buf 0, k0 = 0)
    {
      bf16* kb = Ks + wave * 512;
      bf16* vb = Vs + wave * 512;
      gload_lds16(srcK0, kb);
      gload_lds16(srcK1, kb + 2048);
      gload_lds16(srcV0, vb);
      gload_lds16(srcV1, vb + 2048);
    }
    __syncthreads();
    int cur = 0;
    for (int st = 0; st < nst; ++st) {
      const int k0 = st * 64;
      if (st + 1 < nst) {
        const int kn = k0 + 64;
        bf16* kb = Ks + (cur ^ 1) * 4096 + wave * 512;
        bf16* vb = Vs + (cur ^ 1) * 4096 + wave * 512;
        gload_lds16(srcK0 + (size_t)kn * QKVLD, kb);
        gload_lds16(srcK1 + (size_t)kn * QKVLD, kb + 2048);
        gload_lds16(srcV0 + kn, vb);
        gload_lds16(srcV1 + kn, vb + 2048);
      }
      const bf16* Kb = Ks + cur * 4096;
      const bf16* Vb = Vs + cur * 4096;
      f32x4 c0 = {}, c1 = {}, c2 = {}, c3 = {};
      c0 = mfma32(*(const bf16x8*)(Kb + oKa0), qf0, c0);
      c1 = mfma32(*(const bf16x8*)(Kb + oKa1), qf0, c1);
      c2 = mfma32(*(const bf16x8*)(Kb + oKa2), qf0, c2);
      c3 = mfma32(*(const bf16x8*)(Kb + oKa3), qf0, c3);
      c0 = mfma32(*(const bf16x8*)(Kb + oKb0), qf1, c0);
      c1 = mfma32(*(const bf16x8*)(Kb + oKb1), qf1, c1);
      c2 = mfma32(*(const bf16x8*)(Kb + oKb2), qf1, c2);
      c3 = mfma32(*(const bf16x8*)(Kb + oKb3), qf1, c3);
      // lane holds S^T: c0[j]->k0+8g+j, c1[j]->k0+8g+4+j,
      //                 c2[j]->k0+32+8g+j, c3[j]->k0+32+8g+4+j, q=q0+r
      float p0[4], p1[4], p2[4], p3[4];
      float tmax = -3.0e38f;
      const bool need_mask = (k0 + 63 > qg);
      #pragma unroll
      for (int j = 0; j < 4; ++j) {
        float s0 = c0[j] * 0.125f;
        float s1 = c1[j] * 0.125f;
        float s2 = c2[j] * 0.125f;
        float s3 = c3[j] * 0.125f;
        if (need_mask) {
          if (k0 + 8*g + j > qg)          s0 = -3.0e38f;
          if (k0 + 8*g + 4 + j > qg)      s1 = -3.0e38f;
          if (k0 + 32 + 8*g + j > qg)     s2 = -3.0e38f;
          if (k0 + 32 + 8*g + 4 + j > qg) s3 = -3.0e38f;
        }
        p0[j] = s0; p1[j] = s1; p2[j] = s2; p3[j] = s3;
        tmax = fmaxf(tmax, fmaxf(fmaxf(s0, s1), fmaxf(s2, s3)));
      }
      tmax = fmaxf(tmax, __shfl_xor(tmax, 16));
      tmax = fmaxf(tmax, __shfl_xor(tmax, 32));
      const float mnew = fmaxf(m, tmax);
      const float sc = __expf(m - mnew);
      float tsum = 0.f;
      #pragma unroll
      for (int j = 0; j < 4; ++j) {
        p0[j] = __expf(p0[j] - mnew);
        p1[j] = __expf(p1[j] - mnew);
        p2[j] = __expf(p2[j] - mnew);
        p3[j] = __expf(p3[j] - mnew);
        tsum += (p0[j] + p1[j]) + (p2[j] + p3[j]);
      }
      tsum += __shfl_xor(tsum, 16);
      tsum += __shfl_xor(tsum, 32);
      l = l * sc + tsum;
      m = mnew;
      bf16x8 pfa, pfb;
      #pragma unroll
      for (int j = 0; j < 4; ++j) {
        pfa[j] = (bf16)p0[j]; pfa[4 + j] = (bf16)p1[j];
        pfb[j] = (bf16)p2[j]; pfb[4 + j] = (bf16)p3[j];
      }
      // rescale O (O rows are q-local = 4g+j; sc lives at lane q=r)
      #pragma unroll
      for (int j = 0; j < 4; ++j) {
        const float scj = __shfl(sc, 4*g + j);
        #pragma unroll
        for (int c = 0; c < 4; ++c) ov[c][j] *= scj;
      }
      #pragma unroll
      for (int c = 0; c < 4; ++c) {
        bf16x8 vfa = *(const bf16x8*)(Vb + (c*16 + r) * 32 + g * 8);
        bf16x8 vfb = *(const bf16x8*)(Vb + 2048 + (c*16 + r) * 32 + g * 8);
        ov[c] = mfma32(pfa, vfa, ov[c]);
        ov[c] = mfma32(pfb, vfb, ov[c]);
      }
      __syncthreads();
      cur ^= 1;
    }
    #pragma unroll
    for (int j = 0; j < 4; ++j) {
      const float lj = __shfl(l, 4*g + j);
      const float inv = 1.f / lj;
      const int row = b*SS + q0 + 4*g + j;
      #pragma unroll
      for (int c = 0; c < 4; ++c)
        ctx[(size_t)row * DD + h*HDIM + c*16 + r] = (bf16)(ov[c][j] * inv);
    }
  }
}

// ---------------- LayerNorm(a + c) * g + b ----------------
__global__ __launch_bounds__(256)
void ln_kernel(const float* __restrict__ a, const float* __restrict__ c,
               const float* __restrict__ gam, const float* __restrict__ bet,
               float* __restrict__ outf, bf16* __restrict__ outb) {
  const int row = blockIdx.x;
  const int tid = threadIdx.x;
  const size_t base = (size_t)row * DD + tid * 4;
  float4 va = *(const float4*)(a + base);
  float4 vc = *(const float4*)(c + base);
  float x0 = va.x + vc.x, x1 = va.y + vc.y, x2 = va.z + vc.z, x3 = va.w + vc.w;
  float s  = x0 + x1 + x2 + x3;
  float s2 = x0*x0 + x1*x1 + x2*x2 + x3*x3;
  #pragma unroll
  for (int off = 32; off > 0; off >>= 1) {
    s  += __shfl_xor(s,  off);
    s2 += __shfl_xor(s2, off);
  }
  __shared__ float red[8];
  const int wv = tid >> 6;
  if ((tid & 63) == 0) { red[wv] = s; red[wv + 4] = s2; }
  __syncthreads();
  s  = red[0] + red[1] + red[2] + red[3];
  s2 = red[4] + red[5] + red[6] + red[7];
  const float mu  = s * (1.f / DD);
  const float var = s2 * (1.f / DD) - mu * mu;
  const float rs  = rsqrtf(var + 1e-5f);
  float4 vg = *(const float4*)(gam + tid * 4);
  float4 vb = *(const float4*)(bet + tid * 4);
  float y0 = (x0 - mu) * rs * vg.x + vb.x;
  float y1 = (x1 - mu) * rs * vg.y + vb.y;
  float y2 = (x2 - mu) * rs * vg.z + vb.z;
  float y3 = (x3 - mu) * rs * vg.w + vb.w;
  float4 yo; yo.x = y0; yo.y = y1; yo.z = y2; yo.w = y3;
  *(float4*)(outf + base) = yo;
  if (outb) {
    bf16x4 ob;
    ob[0] = (bf16)y0; ob[1] = (bf16)y1; ob[2] = (bf16)y2; ob[3] = (bf16)y3;
    *(bf16x4*)(outb + base) = ob;
  }
}

extern "C" void kernel_launch(void* const* d_in, const int* in_sizes, int n_in,
                              void* d_out, int out_size, void* d_ws, size_t ws_size,
                              hipStream_t stream) {
  const float* src  = (const float*)d_in[0];
  const float* Wq   = (const float*)d_in[2];
  const float* bq   = (const float*)d_in[3];
  const float* Wk   = (const float*)d_in[4];
  const float* bk   = (const float*)d_in[5];
  const float* Wv   = (const float*)d_in[6];
  const float* bv   = (const float*)d_in[7];
  const float* Wo   = (const float*)d_in[8];
  const float* bo   = (const float*)d_in[9];
  const float* W1   = (const float*)d_in[10];
  const float* b1   = (const float*)d_in[11];
  const float* W2   = (const float*)d_in[12];
  const float* b2   = (const float*)d_in[13];
  const float* ln1g = (const float*)d_in[14];
  const float* ln1b = (const float*)d_in[15];
  const float* ln2g = (const float*)d_in[16];
  const float* ln2b = (const float*)d_in[17];

  char* ws = (char*)d_ws;
  const size_t MB = 1024 * 1024;
  bf16* wqkvt = (bf16*)(ws + 0 * MB);    // [3072][1024] bf16 = 6MB
  bf16* wot   = (bf16*)(ws + 6 * MB);    // 2MB
  bf16* w1t   = (bf16*)(ws + 8 * MB);    // [FFD][DD] = 8MB
  bf16* w2t   = (bf16*)(ws + 16 * MB);   // [DD][FFD] = 8MB
  bf16* bsrc  = (bf16*)(ws + 24 * MB);   // 8MB; reused as xb
  bf16* xb    = bsrc;
  bf16* qkv   = (bf16*)(ws + 32 * MB);   // [4096][3072] = 24MB
  bf16* vt    = (bf16*)(ws + 56 * MB);   // [32][64][2048] = 8MB
  bf16* ctx   = (bf16*)(ws + 64 * MB);   // 8MB
  bf16* ff1   = qkv;                     // [4096][4096] = 32MB, reuses qkv+vt
  float* xf   = (float*)(ws + 72 * MB);  // 16MB
  float* bqkv = (float*)(ws + 88 * MB);  // 12KB
  float* attn_out = (float*)d_out;       // fp32 scratch in d_out (overwritten by LN2)
  float* ff2  = (float*)d_out;
  float* outp = (float*)d_out;

  // conversions
  cvt_bf16_kernel<<<(MR * DD) / 1024, 256, 0, stream>>>(src, bsrc, MR * DD);
  transpose_w_kernel<<<dim3(32, 32), 256, 0, stream>>>(Wq, wqkvt,             DD, DD);
  transpose_w_kernel<<<dim3(32, 32), 256, 0, stream>>>(Wk, wqkvt + 1024*1024, DD, DD);
  transpose_w_kernel<<<dim3(32, 32), 256, 0, stream>>>(Wv, wqkvt + 2048*1024, DD, DD);
  transpose_w_kernel<<<dim3(32, 32), 256, 0, stream>>>(Wo, wot, DD, DD);
  transpose_w_kernel<<<dim3(128, 32), 256, 0, stream>>>(W1, w1t, DD, FFD);
  transpose_w_kernel<<<dim3(32, 128), 256, 0, stream>>>(W2, w2t, FFD, DD);
  concat_bias_kernel<<<12, 256, 0, stream>>>(bq, bk, bv, bqkv);

  // fused QKV projection: [4096,1024] @ [1024,3072] -> [4096,3072]
  gemm_bt<1, 0><<<dim3(24, 32), 256, 0, stream>>>(bsrc, wqkvt, bqkv, qkv, MR, QKVLD, DD);
  transpose_v_kernel<<<dim3(SS / 32, HDIM / 32, BB * HH), 256, 0, stream>>>(qkv + 2048, vt);

  // attention (Q at col 0, K at col 1024 of qkv)
  attn_kernel<<<dim3(16, BB * HH), 256, 0, stream>>>(qkv, qkv + 1024, vt, ctx);

  // output projection + LN1
  gemm_bt<0, 0><<<dim3(8, 32), 256, 0, stream>>>(ctx, wot, bo, attn_out, MR, DD, DD);
  ln_kernel<<<MR, 256, 0, stream>>>(src, attn_out, ln1g, ln1b, xf, xb);

  // FFN + LN2
  gemm_bt<1, 1><<<dim3(32, 32), 256, 0, stream>>>(xb, w1t, b1, ff1, MR, FFD, DD);
  gemm_bt<0, 0><<<dim3(8, 32), 256, 0, stream>>>(ff1, w2t, b2, ff2, MR, DD, FFD);
  ln_kernel<<<MR, 256, 0, stream>>>(xf, ff2, ln2g, ln2b, outp, (bf16*)nullptr);
}

// Round 4
// 284.461 us; speedup vs baseline: 1.8458x; 1.1131x over previous
//
#include <hip/hip_runtime.h>

#define SS 2048
#define DD 1024
#define HH 16
#define HDIM 64
#define BB 2
#define FFD 4096
#define MR (BB*SS)   // 4096 rows
#define QKVLD 3072   // fused qkv row stride

typedef __bf16 bf16;
typedef __bf16 bf16x4 __attribute__((ext_vector_type(4)));
typedef __bf16 bf16x8 __attribute__((ext_vector_type(8)));
typedef float f32x4 __attribute__((ext_vector_type(4)));

__device__ inline f32x4 mfma32(bf16x8 a, bf16x8 b, f32x4 c) {
  return __builtin_amdgcn_mfma_f32_16x16x32_bf16(a, b, c, 0, 0, 0);
}

__device__ inline void gload_lds16(const void* g, void* l) {
  __builtin_amdgcn_global_load_lds(
      (const __attribute__((address_space(1))) void*)g,
      (__attribute__((address_space(3))) void*)l, 16, 0, 0);
}

// ---------------- fp32 -> bf16 elementwise ----------------
__global__ __launch_bounds__(256)
void cvt_bf16_kernel(const float* __restrict__ in, bf16* __restrict__ out, int n) {
  int i = (blockIdx.x * 256 + threadIdx.x) * 4;
  if (i >= n) return;
  float4 v = *(const float4*)(in + i);
  bf16x4 o;
  o[0] = (bf16)v.x; o[1] = (bf16)v.y; o[2] = (bf16)v.z; o[3] = (bf16)v.w;
  *(bf16x4*)(out + i) = o;
}

// ---------------- concat bias qkv ----------------
__global__ __launch_bounds__(256)
void concat_bias_kernel(const float* __restrict__ bq, const float* __restrict__ bk,
                        const float* __restrict__ bv, float* __restrict__ out) {
  int i = blockIdx.x * 256 + threadIdx.x;
  out[i] = i < 1024 ? bq[i] : (i < 2048 ? bk[i - 1024] : bv[i - 2048]);
}

// ---------------- W [K,N] fp32 -> Wt [N,K] bf16 ----------------
__global__ __launch_bounds__(256)
void transpose_w_kernel(const float* __restrict__ W, bf16* __restrict__ Wt,
                        int K, int N) {
  __shared__ float t[32][33];
  int tx = threadIdx.x & 31, ty = threadIdx.x >> 5;  // 32 x 8
  int n0 = blockIdx.x * 32, k0 = blockIdx.y * 32;
  #pragma unroll
  for (int i = 0; i < 4; ++i)
    t[ty + i*8][tx] = W[(size_t)(k0 + ty + i*8) * N + n0 + tx];
  __syncthreads();
  #pragma unroll
  for (int i = 0; i < 4; ++i)
    Wt[(size_t)(n0 + ty + i*8) * K + k0 + tx] = (bf16)t[tx][ty + i*8];
}

// ---------------- V (cols of qkv2d) -> Vt [B,H,HD,S] bf16 ----------------
__global__ __launch_bounds__(256)
void transpose_v_kernel(const bf16* __restrict__ V2d, bf16* __restrict__ Vt) {
  __shared__ bf16 t[32][33];
  int tx = threadIdx.x & 31, ty = threadIdx.x >> 5;
  int s0 = blockIdx.x * 32, d0 = blockIdx.y * 32;
  int bh = blockIdx.z;
  int b = bh >> 4, h = bh & 15;
  #pragma unroll
  for (int i = 0; i < 4; ++i)
    t[ty + i*8][tx] = V2d[(size_t)(b*SS + s0 + ty + i*8) * QKVLD + h*HDIM + d0 + tx];
  __syncthreads();
  #pragma unroll
  for (int i = 0; i < 4; ++i)
    Vt[((size_t)bh*HDIM + d0 + ty + i*8) * SS + s0 + tx] = t[tx][ty + i*8];
}

// ---------------- GEMM: C[M,N] = A[M,K] @ Bt[N,K]^T + bias ----------------
// XCD-aware bijective swizzle (T1): full-3D linear id, chunk nwg/8 per XCD.
// SPLITK>1: blockIdx.z picks K-chunk; partial fp32 to (z==0 ? Cout : Cout2),
// bias deferred to the consumer.
template<int OUT_BF16, int RELU, int SPLITK>
__global__ __launch_bounds__(256)
void gemm_bt(const bf16* __restrict__ A, const bf16* __restrict__ Bt,
             const float* __restrict__ bias, void* __restrict__ Cout,
             float* __restrict__ Cout2, int Mdim, int Ndim, int Kdim) {
  __shared__ bf16 As[128 * 32];
  __shared__ bf16 Bs[128 * 32];
  const int gx = gridDim.x, gy = gridDim.y;
  const int nwg = gx * gy * gridDim.z;
  const int lin = (blockIdx.z * gy + blockIdx.y) * gx + blockIdx.x;
  const int swz = (lin & 7) * (nwg >> 3) + (lin >> 3);
  const int bz = swz / (gx * gy);
  const int rem = swz - bz * gx * gy;
  const int by = rem / gx;
  const int bx = rem - by * gx;
  const int tid = threadIdx.x;
  const int wave = tid >> 6;
  const int lane = tid & 63;
  const int g = lane >> 4;
  const int r = lane & 15;
  const int m0 = by * 128;
  const int n0 = bx * 128;
  const int kchunk = Kdim / SPLITK;
  const int kstart = bz * kchunk;
  const int wr = wave >> 1, wc = wave & 1;   // 2x2 waves -> 64x64 each
  f32x4 acc[4][4] = {};
  const int strow = tid >> 2;        // 0..63
  const int stcol = (tid & 3) * 8;
  const bf16* Abase = A + (size_t)(m0 + strow) * Kdim + kstart + stcol;
  const bf16* Bbase = Bt + (size_t)(n0 + strow) * Kdim + kstart + stcol;
  bf16* AsW = As + wave * 512;
  bf16* BsW = Bs + wave * 512;
  for (int k0 = 0; k0 < kchunk; k0 += 32) {
    __syncthreads();
    gload_lds16(Abase + k0, AsW);
    gload_lds16(Abase + k0 + (size_t)64 * Kdim, AsW + 2048);
    gload_lds16(Bbase + k0, BsW);
    gload_lds16(Bbase + k0 + (size_t)64 * Kdim, BsW + 2048);
    __syncthreads();
    bf16x8 af[4], bfr[4];
    #pragma unroll
    for (int i = 0; i < 4; ++i)
      af[i] = *(const bf16x8*)(As + (wr*64 + i*16 + r) * 32 + g * 8);
    #pragma unroll
    for (int i = 0; i < 4; ++i)
      bfr[i] = *(const bf16x8*)(Bs + (wc*64 + i*16 + r) * 32 + g * 8);
    #pragma unroll
    for (int mi = 0; mi < 4; ++mi)
      #pragma unroll
      for (int ni = 0; ni < 4; ++ni)
        acc[mi][ni] = mfma32(af[mi], bfr[ni], acc[mi][ni]);
  }
  float* outp = (SPLITK > 1 && bz) ? Cout2 : (float*)Cout;
  #pragma unroll
  for (int mi = 0; mi < 4; ++mi) {
    #pragma unroll
    for (int ni = 0; ni < 4; ++ni) {
      const int col = n0 + wc*64 + ni*16 + r;
      const float bv = (SPLITK > 1) ? 0.f : bias[col];
      #pragma unroll
      for (int j = 0; j < 4; ++j) {
        const int row = m0 + wr*64 + mi*16 + g*4 + j;
        float v = acc[mi][ni][j] + bv;
        if (RELU) v = fmaxf(v, 0.f);
        if (OUT_BF16) ((bf16*)Cout)[(size_t)row * Ndim + col] = (bf16)v;
        else          outp[(size_t)row * Ndim + col] = v;
      }
    }
  }
}

// ---------------- flash attention: LDS-staged K/V, double-buffered ----------------
__global__ __launch_bounds__(256)
void attn_kernel(const bf16* __restrict__ Q2d, const bf16* __restrict__ K2d,
                 const bf16* __restrict__ Vt, bf16* __restrict__ ctx) {
  __shared__ bf16 Ks[2 * 4096];   // 2 bufs x [2 halves][64][32]
  __shared__ bf16 Vs[2 * 4096];
  const int tid = threadIdx.x;
  const int wave = tid >> 6;
  const int lane = tid & 63;
  const int g = lane >> 4, r = lane & 15;
  const int p = blockIdx.x;          // 0..15 (pair index)
  const int bh = blockIdx.y;         // 0..31
  const int b = bh >> 4, h = bh & 15;

  const int strow = wave * 16 + (lane >> 2);   // 0..63
  const int stcol = (lane & 3) * 8;            // 0,8,16,24
  const bf16* srcK0 = K2d + (size_t)(b*SS + strow) * QKVLD + h*HDIM + stcol;
  const bf16* srcK1 = srcK0 + 32;
  const bf16* srcV0 = Vt + ((size_t)bh*HDIM + strow) * SS + stcol;
  const bf16* srcV1 = srcV0 + 32;

  const int kr0 = 8 * (r >> 2) + (r & 3);      // permuted K row for S^T frag
  const int oKa0 = (kr0     ) * 32 + g * 8, oKb0 = 2048 + oKa0;
  const int oKa1 = (kr0 +  4) * 32 + g * 8, oKb1 = 2048 + oKa1;
  const int oKa2 = (kr0 + 32) * 32 + g * 8, oKb2 = 2048 + oKa2;
  const int oKa3 = (kr0 + 36) * 32 + g * 8, oKb3 = 2048 + oKa3;

  #pragma unroll
  for (int tt = 0; tt < 2; ++tt) {
    const int tile = tt ? (31 - p) : p;
    const int q0 = tile * 64 + wave * 16;
    const int qg = q0 + r;
    const bf16* qp = Q2d + (size_t)(b*SS + q0 + r) * QKVLD + h * HDIM;
    const bf16x8 qf0 = *(const bf16x8*)(qp + g * 8);
    const bf16x8 qf1 = *(const bf16x8*)(qp + 32 + g * 8);
    f32x4 ov[4] = {};
    float m = -3.0e38f, l = 0.f;
    const int nst = tile + 1;
    {
      bf16* kb = Ks + wave * 512;
      bf16* vb = Vs + wave * 512;
      gload_lds16(srcK0, kb);
      gload_lds16(srcK1, kb + 2048);
      gload_lds16(srcV0, vb);
      gload_lds16(srcV1, vb + 2048);
    }
    __syncthreads();
    int cur = 0;
    for (int st = 0; st < nst; ++st) {
      const int k0 = st * 64;
      if (st + 1 < nst) {
        const int kn = k0 + 64;
        bf16* kb = Ks + (cur ^ 1) * 4096 + wave * 512;
        bf16* vb = Vs + (cur ^ 1) * 4096 + wave * 512;
        gload_lds16(srcK0 + (size_t)kn * QKVLD, kb);
        gload_lds16(srcK1 + (size_t)kn * QKVLD, kb + 2048);
        gload_lds16(srcV0 + kn, vb);
        gload_lds16(srcV1 + kn, vb + 2048);
      }
      const bf16* Kb = Ks + cur * 4096;
      const bf16* Vb = Vs + cur * 4096;
      f32x4 c0 = {}, c1 = {}, c2 = {}, c3 = {};
      c0 = mfma32(*(const bf16x8*)(Kb + oKa0), qf0, c0);
      c1 = mfma32(*(const bf16x8*)(Kb + oKa1), qf0, c1);
      c2 = mfma32(*(const bf16x8*)(Kb + oKa2), qf0, c2);
      c3 = mfma32(*(const bf16x8*)(Kb + oKa3), qf0, c3);
      c0 = mfma32(*(const bf16x8*)(Kb + oKb0), qf1, c0);
      c1 = mfma32(*(const bf16x8*)(Kb + oKb1), qf1, c1);
      c2 = mfma32(*(const bf16x8*)(Kb + oKb2), qf1, c2);
      c3 = mfma32(*(const bf16x8*)(Kb + oKb3), qf1, c3);
      float p0[4], p1[4], p2[4], p3[4];
      float tmax = -3.0e38f;
      const bool need_mask = (k0 + 63 > qg);
      #pragma unroll
      for (int j = 0; j < 4; ++j) {
        float s0 = c0[j] * 0.125f;
        float s1 = c1[j] * 0.125f;
        float s2 = c2[j] * 0.125f;
        float s3 = c3[j] * 0.125f;
        if (need_mask) {
          if (k0 + 8*g + j > qg)          s0 = -3.0e38f;
          if (k0 + 8*g + 4 + j > qg)      s1 = -3.0e38f;
          if (k0 + 32 + 8*g + j > qg)     s2 = -3.0e38f;
          if (k0 + 32 + 8*g + 4 + j > qg) s3 = -3.0e38f;
        }
        p0[j] = s0; p1[j] = s1; p2[j] = s2; p3[j] = s3;
        tmax = fmaxf(tmax, fmaxf(fmaxf(s0, s1), fmaxf(s2, s3)));
      }
      tmax = fmaxf(tmax, __shfl_xor(tmax, 16));
      tmax = fmaxf(tmax, __shfl_xor(tmax, 32));
      const float mnew = fmaxf(m, tmax);
      const float sc = __expf(m - mnew);
      float tsum = 0.f;
      #pragma unroll
      for (int j = 0; j < 4; ++j) {
        p0[j] = __expf(p0[j] - mnew);
        p1[j] = __expf(p1[j] - mnew);
        p2[j] = __expf(p2[j] - mnew);
        p3[j] = __expf(p3[j] - mnew);
        tsum += (p0[j] + p1[j]) + (p2[j] + p3[j]);
      }
      tsum += __shfl_xor(tsum, 16);
      tsum += __shfl_xor(tsum, 32);
      l = l * sc + tsum;
      m = mnew;
      bf16x8 pfa, pfb;
      #pragma unroll
      for (int j = 0; j < 4; ++j) {
        pfa[j] = (bf16)p0[j]; pfa[4 + j] = (bf16)p1[j];
        pfb[j] = (bf16)p2[j]; pfb[4 + j] = (bf16)p3[j];
      }
      #pragma unroll
      for (int j = 0; j < 4; ++j) {
        const float scj = __shfl(sc, 4*g + j);
        #pragma unroll
        for (int c = 0; c < 4; ++c) ov[c][j] *= scj;
      }
      #pragma unroll
      for (int c = 0; c < 4; ++c) {
        bf16x8 vfa = *(const bf16x8*)(Vb + (c*16 + r) * 32 + g * 8);
        bf16x8 vfb = *(const bf16x8*)(Vb + 2048 + (c*16 + r) * 32 + g * 8);
        ov[c] = mfma32(pfa, vfa, ov[c]);
        ov[c] = mfma32(pfb, vfb, ov[c]);
      }
      __syncthreads();
      cur ^= 1;
    }
    #pragma unroll
    for (int j = 0; j < 4; ++j) {
      const float lj = __shfl(l, 4*g + j);
      const float inv = 1.f / lj;
      const int row = b*SS + q0 + 4*g + j;
      #pragma unroll
      for (int c = 0; c < 4; ++c)
        ctx[(size_t)row * DD + h*HDIM + c*16 + r] = (bf16)(ov[c][j] * inv);
    }
  }
}

// ---------------- LayerNorm(a + p0 [+ p1 + colbias]) * g + b ----------------
template<int NP, int HASB, int WRITEB>
__global__ __launch_bounds__(256)
void ln_kernel(const float* __restrict__ a, const float* __restrict__ p0,
               const float* __restrict__ p1, const float* __restrict__ cb,
               const float* __restrict__ gam, const float* __restrict__ bet,
               float* __restrict__ outf, bf16* __restrict__ outb) {
  const int row = blockIdx.x;
  const int tid = threadIdx.x;
  const size_t base = (size_t)row * DD + tid * 4;
  float4 va = *(const float4*)(a + base);
  float4 vc = *(const float4*)(p0 + base);
  float x0 = va.x + vc.x, x1 = va.y + vc.y, x2 = va.z + vc.z, x3 = va.w + vc.w;
  if (NP > 1) {
    float4 vp = *(const float4*)(p1 + base);
    x0 += vp.x; x1 += vp.y; x2 += vp.z; x3 += vp.w;
  }
  if (HASB) {
    float4 vb4 = *(const float4*)(cb + tid * 4);
    x0 += vb4.x; x1 += vb4.y; x2 += vb4.z; x3 += vb4.w;
  }
  float s  = x0 + x1 + x2 + x3;
  float s2 = x0*x0 + x1*x1 + x2*x2 + x3*x3;
  #pragma unroll
  for (int off = 32; off > 0; off >>= 1) {
    s  += __shfl_xor(s,  off);
    s2 += __shfl_xor(s2, off);
  }
  __shared__ float red[8];
  const int wv = tid >> 6;
  if ((tid & 63) == 0) { red[wv] = s; red[wv + 4] = s2; }
  __syncthreads();
  s  = red[0] + red[1] + red[2] + red[3];
  s2 = red[4] + red[5] + red[6] + red[7];
  const float mu  = s * (1.f / DD);
  const float var = s2 * (1.f / DD) - mu * mu;
  const float rs  = rsqrtf(var + 1e-5f);
  float4 vg = *(const float4*)(gam + tid * 4);
  float4 vb = *(const float4*)(bet + tid * 4);
  float y0 = (x0 - mu) * rs * vg.x + vb.x;
  float y1 = (x1 - mu) * rs * vg.y + vb.y;
  float y2 = (x2 - mu) * rs * vg.z + vb.z;
  float y3 = (x3 - mu) * rs * vg.w + vb.w;
  float4 yo; yo.x = y0; yo.y = y1; yo.z = y2; yo.w = y3;
  *(float4*)(outf + base) = yo;
  if (WRITEB) {
    bf16x4 ob;
    ob[0] = (bf16)y0; ob[1] = (bf16)y1; ob[2] = (bf16)y2; ob[3] = (bf16)y3;
    *(bf16x4*)(outb + base) = ob;
  }
}

extern "C" void kernel_launch(void* const* d_in, const int* in_sizes, int n_in,
                              void* d_out, int out_size, void* d_ws, size_t ws_size,
                              hipStream_t stream) {
  const float* src  = (const float*)d_in[0];
  const float* Wq   = (const float*)d_in[2];
  const float* bq   = (const float*)d_in[3];
  const float* Wk   = (const float*)d_in[4];
  const float* bk   = (const float*)d_in[5];
  const float* Wv   = (const float*)d_in[6];
  const float* bv   = (const float*)d_in[7];
  const float* Wo   = (const float*)d_in[8];
  const float* bo   = (const float*)d_in[9];
  const float* W1   = (const float*)d_in[10];
  const float* b1   = (const float*)d_in[11];
  const float* W2   = (const float*)d_in[12];
  const float* b2   = (const float*)d_in[13];
  const float* ln1g = (const float*)d_in[14];
  const float* ln1b = (const float*)d_in[15];
  const float* ln2g = (const float*)d_in[16];
  const float* ln2b = (const float*)d_in[17];

  char* ws = (char*)d_ws;
  const size_t MB = 1024 * 1024;
  bf16* wqkvt = (bf16*)(ws + 0 * MB);    // [3072][1024] bf16 = 6MB (dead after QKV)
  bf16* wot   = (bf16*)(ws + 6 * MB);    // 2MB (dead after Wo)
  bf16* w1t   = (bf16*)(ws + 8 * MB);    // 8MB (dead after FF1)
  bf16* w2t   = (bf16*)(ws + 16 * MB);   // 8MB
  bf16* bsrc  = (bf16*)(ws + 24 * MB);   // 8MB; reused as xb
  bf16* xb    = bsrc;
  bf16* qkv   = (bf16*)(ws + 32 * MB);   // [4096][3072] = 24MB
  bf16* vt    = (bf16*)(ws + 56 * MB);   // 8MB
  bf16* ctx   = (bf16*)(ws + 64 * MB);   // 8MB
  bf16* ff1   = qkv;                     // [4096][4096] = 32MB, reuses qkv+vt
  float* xf   = (float*)(ws + 72 * MB);  // 16MB
  float* bqkv = (float*)(ws + 88 * MB);  // 12KB
  float* ff2p1 = (float*)(ws + 0 * MB);  // 16MB partial over dead wqkvt/wot/w1t
  float* attn_out = (float*)d_out;       // fp32 scratch in d_out
  float* ff2p0 = (float*)d_out;
  float* outp  = (float*)d_out;

  // conversions
  cvt_bf16_kernel<<<(MR * DD) / 1024, 256, 0, stream>>>(src, bsrc, MR * DD);
  transpose_w_kernel<<<dim3(32, 32), 256, 0, stream>>>(Wq, wqkvt,             DD, DD);
  transpose_w_kernel<<<dim3(32, 32), 256, 0, stream>>>(Wk, wqkvt + 1024*1024, DD, DD);
  transpose_w_kernel<<<dim3(32, 32), 256, 0, stream>>>(Wv, wqkvt + 2048*1024, DD, DD);
  transpose_w_kernel<<<dim3(32, 32), 256, 0, stream>>>(Wo, wot, DD, DD);
  transpose_w_kernel<<<dim3(128, 32), 256, 0, stream>>>(W1, w1t, DD, FFD);
  transpose_w_kernel<<<dim3(32, 128), 256, 0, stream>>>(W2, w2t, FFD, DD);
  concat_bias_kernel<<<12, 256, 0, stream>>>(bq, bk, bv, bqkv);

  // fused QKV projection: [4096,1024] @ [1024,3072] -> [4096,3072]
  gemm_bt<1, 0, 1><<<dim3(24, 32), 256, 0, stream>>>(bsrc, wqkvt, bqkv, qkv, nullptr, MR, QKVLD, DD);
  transpose_v_kernel<<<dim3(SS / 32, HDIM / 32, BB * HH), 256, 0, stream>>>(qkv + 2048, vt);

  // attention (Q at col 0, K at col 1024 of qkv)
  attn_kernel<<<dim3(16, BB * HH), 256, 0, stream>>>(qkv, qkv + 1024, vt, ctx);

  // output projection + LN1
  gemm_bt<0, 0, 1><<<dim3(8, 32), 256, 0, stream>>>(ctx, wot, bo, attn_out, nullptr, MR, DD, DD);
  ln_kernel<1, 0, 1><<<MR, 256, 0, stream>>>(src, attn_out, nullptr, nullptr, ln1g, ln1b, xf, xb);

  // FFN: FF1 full, FF2 split-K=2 (partials: d_out + ws0), reduce fused in LN2
  gemm_bt<1, 1, 1><<<dim3(32, 32), 256, 0, stream>>>(xb, w1t, b1, ff1, nullptr, MR, FFD, DD);
  gemm_bt<0, 0, 2><<<dim3(8, 32, 2), 256, 0, stream>>>(ff1, w2t, nullptr, ff2p0, ff2p1, MR, DD, FFD);
  ln_kernel<2, 1, 0><<<MR, 256, 0, stream>>>(xf, ff2p0, ff2p1, b2, ln2g, ln2b, outp, (bf16*)nullptr);
}

// Round 5
// 278.114 us; speedup vs baseline: 1.8879x; 1.0228x over previous
//
#include <hip/hip_runtime.h>

#define SS 2048
#define DD 1024
#define HH 16
#define HDIM 64
#define BB 2
#define FFD 4096
#define MR (BB*SS)   // 4096 rows
#define QKVLD 3072   // fused qkv row stride

typedef __bf16 bf16;
typedef __bf16 bf16x4 __attribute__((ext_vector_type(4)));
typedef __bf16 bf16x8 __attribute__((ext_vector_type(8)));
typedef float f32x4 __attribute__((ext_vector_type(4)));

__device__ inline f32x4 mfma32(bf16x8 a, bf16x8 b, f32x4 c) {
  return __builtin_amdgcn_mfma_f32_16x16x32_bf16(a, b, c, 0, 0, 0);
}

__device__ inline void gload_lds16(const void* g, void* l) {
  __builtin_amdgcn_global_load_lds(
      (const __attribute__((address_space(1))) void*)g,
      (__attribute__((address_space(3))) void*)l, 16, 0, 0);
}

// ---------------- fp32 -> bf16 elementwise ----------------
__global__ __launch_bounds__(256)
void cvt_bf16_kernel(const float* __restrict__ in, bf16* __restrict__ out, int n) {
  int i = (blockIdx.x * 256 + threadIdx.x) * 4;
  if (i >= n) return;
  float4 v = *(const float4*)(in + i);
  bf16x4 o;
  o[0] = (bf16)v.x; o[1] = (bf16)v.y; o[2] = (bf16)v.z; o[3] = (bf16)v.w;
  *(bf16x4*)(out + i) = o;
}

// ---------------- concat bias qkv ----------------
__global__ __launch_bounds__(256)
void concat_bias_kernel(const float* __restrict__ bq, const float* __restrict__ bk,
                        const float* __restrict__ bv, float* __restrict__ out) {
  int i = blockIdx.x * 256 + threadIdx.x;
  out[i] = i < 1024 ? bq[i] : (i < 2048 ? bk[i - 1024] : bv[i - 2048]);
}

// ---------------- W [K,N] fp32 -> Wt [N,K] bf16 ----------------
__global__ __launch_bounds__(256)
void transpose_w_kernel(const float* __restrict__ W, bf16* __restrict__ Wt,
                        int K, int N) {
  __shared__ float t[32][33];
  int tx = threadIdx.x & 31, ty = threadIdx.x >> 5;  // 32 x 8
  int n0 = blockIdx.x * 32, k0 = blockIdx.y * 32;
  #pragma unroll
  for (int i = 0; i < 4; ++i)
    t[ty + i*8][tx] = W[(size_t)(k0 + ty + i*8) * N + n0 + tx];
  __syncthreads();
  #pragma unroll
  for (int i = 0; i < 4; ++i)
    Wt[(size_t)(n0 + ty + i*8) * K + k0 + tx] = (bf16)t[tx][ty + i*8];
}

// ---------------- V (cols of qkv2d) -> Vt [B,H,HD,S] bf16 ----------------
__global__ __launch_bounds__(256)
void transpose_v_kernel(const bf16* __restrict__ V2d, bf16* __restrict__ Vt) {
  __shared__ bf16 t[32][33];
  int tx = threadIdx.x & 31, ty = threadIdx.x >> 5;
  int s0 = blockIdx.x * 32, d0 = blockIdx.y * 32;
  int bh = blockIdx.z;
  int b = bh >> 4, h = bh & 15;
  #pragma unroll
  for (int i = 0; i < 4; ++i)
    t[ty + i*8][tx] = V2d[(size_t)(b*SS + s0 + ty + i*8) * QKVLD + h*HDIM + d0 + tx];
  __syncthreads();
  #pragma unroll
  for (int i = 0; i < 4; ++i)
    Vt[((size_t)bh*HDIM + d0 + ty + i*8) * SS + s0 + tx] = t[tx][ty + i*8];
}

// ======== 256x256 deep-pipelined GEMM: C[M,N] = A[M,K] @ Bt[N,K]^T + bias ========
// 512 thr / 8 waves (2Mx4N), BK=64, 128KB LDS dbuf, T2 slot-swizzle
// (phys_slot = kslot ^ (row&7), applied inverse on global src + on ds_read),
// 4 quadrant-phases per K-tile with raw s_barrier + setprio(1) MFMA clusters,
// next-tile prefetch front-loaded at phase 0, per-tile vmcnt(0)+barrier boundary.
template<int OUT_BF16, int RELU>
__global__ __launch_bounds__(512)
void gemm256(const bf16* __restrict__ A, const bf16* __restrict__ Bt,
             const float* __restrict__ bias, void* __restrict__ Cout,
             int Ndim, int Kdim) {
  __shared__ bf16 Asm[2][256 * 64];
  __shared__ bf16 Bsm[2][256 * 64];
  const int gx = gridDim.x;
  const int nwg = gx * gridDim.y;
  const int lin = blockIdx.y * gx + blockIdx.x;
  const int swz = (lin & 7) * (nwg >> 3) + (lin >> 3);
  const int by = swz / gx, bx = swz - by * gx;
  const int m0 = by * 256, n0 = bx * 256;
  const int tid = threadIdx.x;
  const int wave = tid >> 6, lane = tid & 63;
  const int g = lane >> 4, r = lane & 15;
  const int wr = wave >> 2, wn = wave & 3;

  // staging: issue j covers rows [j*64 + wave*8, +8); lane>>3 = row offset,
  // lane&7 = phys slot; logical k-slot = (lane&7) ^ (lane>>3) (row&7 == lane>>3)
  const int srow = wave * 8 + (lane >> 3);
  const int skslot = (lane & 7) ^ (lane >> 3);
  const bf16* Ag = A + (size_t)(m0 + srow) * Kdim + skslot * 8;
  const bf16* Bg = Bt + (size_t)(n0 + srow) * Kdim + skslot * 8;

  f32x4 acc[8][4] = {};
  const int NT = Kdim >> 6;

  auto stage = [&](int t) {
    const int kb = t << 6;
    bf16* Ad = Asm[t & 1];
    bf16* Bd = Bsm[t & 1];
    #pragma unroll
    for (int j = 0; j < 4; ++j)
      gload_lds16(Ag + (size_t)j * 64 * Kdim + kb, Ad + (j * 64 + wave * 8) * 64);
    #pragma unroll
    for (int j = 0; j < 4; ++j)
      gload_lds16(Bg + (size_t)j * 64 * Kdim + kb, Bd + (j * 64 + wave * 8) * 64);
  };

  stage(0);
  asm volatile("s_waitcnt vmcnt(0)" ::: "memory");
  asm volatile("s_barrier" ::: "memory");

  for (int t = 0; t < NT; ++t) {
    const bf16* Ab = Asm[t & 1];
    const bf16* Bb = Bsm[t & 1];
    #pragma unroll
    for (int ph = 0; ph < 4; ++ph) {
      const int mq = ph >> 1, nq = ph & 1;
      bf16x8 af[4][2], bfr[2][2];
      #pragma unroll
      for (int i = 0; i < 4; ++i) {
        const int row = wr * 128 + (mq * 4 + i) * 16 + r;   // row&7 == r&7
        #pragma unroll
        for (int kk = 0; kk < 2; ++kk)
          af[i][kk] = *(const bf16x8*)(Ab + row * 64 + (((kk * 4 + g) ^ (r & 7)) * 8));
      }
      #pragma unroll
      for (int i = 0; i < 2; ++i) {
        const int rowb = wn * 64 + (nq * 2 + i) * 16 + r;
        #pragma unroll
        for (int kk = 0; kk < 2; ++kk)
          bfr[i][kk] = *(const bf16x8*)(Bb + rowb * 64 + (((kk * 4 + g) ^ (r & 7)) * 8));
      }
      if (ph == 0 && t + 1 < NT) stage(t + 1);
      asm volatile("s_barrier" ::: "memory");
      __builtin_amdgcn_s_setprio(1);
      #pragma unroll
      for (int i = 0; i < 4; ++i)
        #pragma unroll
        for (int jn = 0; jn < 2; ++jn)
          #pragma unroll
          for (int kk = 0; kk < 2; ++kk)
            acc[mq * 4 + i][nq * 2 + jn] =
                mfma32(af[i][kk], bfr[jn][kk], acc[mq * 4 + i][nq * 2 + jn]);
      __builtin_amdgcn_s_setprio(0);
      asm volatile("s_barrier" ::: "memory");
    }
    asm volatile("s_waitcnt vmcnt(0)" ::: "memory");
    asm volatile("s_barrier" ::: "memory");
  }

  #pragma unroll
  for (int mi = 0; mi < 8; ++mi) {
    #pragma unroll
    for (int ni = 0; ni < 4; ++ni) {
      const int col = n0 + wn * 64 + ni * 16 + r;
      const float bv = bias[col];
      #pragma unroll
      for (int jj = 0; jj < 4; ++jj) {
        const int row = m0 + wr * 128 + mi * 16 + g * 4 + jj;
        float v = acc[mi][ni][jj] + bv;
        if (RELU) v = fmaxf(v, 0.f);
        if (OUT_BF16) ((bf16*)Cout)[(size_t)row * Ndim + col] = (bf16)v;
        else          ((float*)Cout)[(size_t)row * Ndim + col] = v;
      }
    }
  }
}

// ---------------- GEMM 128^2 (m97 structure): used for Wo + FF2 split-K ----------------
template<int OUT_BF16, int RELU, int SPLITK>
__global__ __launch_bounds__(256)
void gemm_bt(const bf16* __restrict__ A, const bf16* __restrict__ Bt,
             const float* __restrict__ bias, void* __restrict__ Cout,
             float* __restrict__ Cout2, int Mdim, int Ndim, int Kdim) {
  __shared__ bf16 As[128 * 32];
  __shared__ bf16 Bs[128 * 32];
  const int gx = gridDim.x, gy = gridDim.y;
  const int nwg = gx * gy * gridDim.z;
  const int lin = (blockIdx.z * gy + blockIdx.y) * gx + blockIdx.x;
  const int swz = (lin & 7) * (nwg >> 3) + (lin >> 3);
  const int bz = swz / (gx * gy);
  const int rem = swz - bz * gx * gy;
  const int by = rem / gx;
  const int bx = rem - by * gx;
  const int tid = threadIdx.x;
  const int wave = tid >> 6;
  const int lane = tid & 63;
  const int g = lane >> 4;
  const int r = lane & 15;
  const int m0 = by * 128;
  const int n0 = bx * 128;
  const int kchunk = Kdim / SPLITK;
  const int kstart = bz * kchunk;
  const int wr = wave >> 1, wc = wave & 1;   // 2x2 waves -> 64x64 each
  f32x4 acc[4][4] = {};
  const int strow = tid >> 2;        // 0..63
  const int stcol = (tid & 3) * 8;
  const bf16* Abase = A + (size_t)(m0 + strow) * Kdim + kstart + stcol;
  const bf16* Bbase = Bt + (size_t)(n0 + strow) * Kdim + kstart + stcol;
  bf16* AsW = As + wave * 512;
  bf16* BsW = Bs + wave * 512;
  for (int k0 = 0; k0 < kchunk; k0 += 32) {
    __syncthreads();
    gload_lds16(Abase + k0, AsW);
    gload_lds16(Abase + k0 + (size_t)64 * Kdim, AsW + 2048);
    gload_lds16(Bbase + k0, BsW);
    gload_lds16(Bbase + k0 + (size_t)64 * Kdim, BsW + 2048);
    __syncthreads();
    bf16x8 af[4], bfr[4];
    #pragma unroll
    for (int i = 0; i < 4; ++i)
      af[i] = *(const bf16x8*)(As + (wr*64 + i*16 + r) * 32 + g * 8);
    #pragma unroll
    for (int i = 0; i < 4; ++i)
      bfr[i] = *(const bf16x8*)(Bs + (wc*64 + i*16 + r) * 32 + g * 8);
    #pragma unroll
    for (int mi = 0; mi < 4; ++mi)
      #pragma unroll
      for (int ni = 0; ni < 4; ++ni)
        acc[mi][ni] = mfma32(af[mi], bfr[ni], acc[mi][ni]);
  }
  float* outp = (SPLITK > 1 && bz) ? Cout2 : (float*)Cout;
  #pragma unroll
  for (int mi = 0; mi < 4; ++mi) {
    #pragma unroll
    for (int ni = 0; ni < 4; ++ni) {
      const int col = n0 + wc*64 + ni*16 + r;
      const float bv = (SPLITK > 1) ? 0.f : bias[col];
      #pragma unroll
      for (int j = 0; j < 4; ++j) {
        const int row = m0 + wr*64 + mi*16 + g*4 + j;
        float v = acc[mi][ni][j] + bv;
        if (RELU) v = fmaxf(v, 0.f);
        if (OUT_BF16) ((bf16*)Cout)[(size_t)row * Ndim + col] = (bf16)v;
        else          outp[(size_t)row * Ndim + col] = v;
      }
    }
  }
}

// ---------------- flash attention: LDS-staged K/V, double-buffered ----------------
__global__ __launch_bounds__(256)
void attn_kernel(const bf16* __restrict__ Q2d, const bf16* __restrict__ K2d,
                 const bf16* __restrict__ Vt, bf16* __restrict__ ctx) {
  __shared__ bf16 Ks[2 * 4096];   // 2 bufs x [2 halves][64][32]
  __shared__ bf16 Vs[2 * 4096];
  const int tid = threadIdx.x;
  const int wave = tid >> 6;
  const int lane = tid & 63;
  const int g = lane >> 4, r = lane & 15;
  const int p = blockIdx.x;          // 0..15 (pair index)
  const int bh = blockIdx.y;         // 0..31
  const int b = bh >> 4, h = bh & 15;

  const int strow = wave * 16 + (lane >> 2);   // 0..63
  const int stcol = (lane & 3) * 8;            // 0,8,16,24
  const bf16* srcK0 = K2d + (size_t)(b*SS + strow) * QKVLD + h*HDIM + stcol;
  const bf16* srcK1 = srcK0 + 32;
  const bf16* srcV0 = Vt + ((size_t)bh*HDIM + strow) * SS + stcol;
  const bf16* srcV1 = srcV0 + 32;

  const int kr0 = 8 * (r >> 2) + (r & 3);      // permuted K row for S^T frag
  const int oKa0 = (kr0     ) * 32 + g * 8, oKb0 = 2048 + oKa0;
  const int oKa1 = (kr0 +  4) * 32 + g * 8, oKb1 = 2048 + oKa1;
  const int oKa2 = (kr0 + 32) * 32 + g * 8, oKb2 = 2048 + oKa2;
  const int oKa3 = (kr0 + 36) * 32 + g * 8, oKb3 = 2048 + oKa3;

  #pragma unroll
  for (int tt = 0; tt < 2; ++tt) {
    const int tile = tt ? (31 - p) : p;
    const int q0 = tile * 64 + wave * 16;
    const int qg = q0 + r;
    const bf16* qp = Q2d + (size_t)(b*SS + q0 + r) * QKVLD + h * HDIM;
    const bf16x8 qf0 = *(const bf16x8*)(qp + g * 8);
    const bf16x8 qf1 = *(const bf16x8*)(qp + 32 + g * 8);
    f32x4 ov[4] = {};
    float m = -3.0e38f, l = 0.f;
    const int nst = tile + 1;
    {
      bf16* kb = Ks + wave * 512;
      bf16* vb = Vs + wave * 512;
      gload_lds16(srcK0, kb);
      gload_lds16(srcK1, kb + 2048);
      gload_lds16(srcV0, vb);
      gload_lds16(srcV1, vb + 2048);
    }
    __syncthreads();
    int cur = 0;
    for (int st = 0; st < nst; ++st) {
      const int k0 = st * 64;
      if (st + 1 < nst) {
        const int kn = k0 + 64;
        bf16* kb = Ks + (cur ^ 1) * 4096 + wave * 512;
        bf16* vb = Vs + (cur ^ 1) * 4096 + wave * 512;
        gload_lds16(srcK0 + (size_t)kn * QKVLD, kb);
        gload_lds16(srcK1 + (size_t)kn * QKVLD, kb + 2048);
        gload_lds16(srcV0 + kn, vb);
        gload_lds16(srcV1 + kn, vb + 2048);
      }
      const bf16* Kb = Ks + cur * 4096;
      const bf16* Vb = Vs + cur * 4096;
      f32x4 c0 = {}, c1 = {}, c2 = {}, c3 = {};
      c0 = mfma32(*(const bf16x8*)(Kb + oKa0), qf0, c0);
      c1 = mfma32(*(const bf16x8*)(Kb + oKa1), qf0, c1);
      c2 = mfma32(*(const bf16x8*)(Kb + oKa2), qf0, c2);
      c3 = mfma32(*(const bf16x8*)(Kb + oKa3), qf0, c3);
      c0 = mfma32(*(const bf16x8*)(Kb + oKb0), qf1, c0);
      c1 = mfma32(*(const bf16x8*)(Kb + oKb1), qf1, c1);
      c2 = mfma32(*(const bf16x8*)(Kb + oKb2), qf1, c2);
      c3 = mfma32(*(const bf16x8*)(Kb + oKb3), qf1, c3);
      float p0[4], p1[4], p2[4], p3[4];
      float tmax = -3.0e38f;
      const bool need_mask = (k0 + 63 > qg);
      #pragma unroll
      for (int j = 0; j < 4; ++j) {
        float s0 = c0[j] * 0.125f;
        float s1 = c1[j] * 0.125f;
        float s2 = c2[j] * 0.125f;
        float s3 = c3[j] * 0.125f;
        if (need_mask) {
          if (k0 + 8*g + j > qg)          s0 = -3.0e38f;
          if (k0 + 8*g + 4 + j > qg)      s1 = -3.0e38f;
          if (k0 + 32 + 8*g + j > qg)     s2 = -3.0e38f;
          if (k0 + 32 + 8*g + 4 + j > qg) s3 = -3.0e38f;
        }
        p0[j] = s0; p1[j] = s1; p2[j] = s2; p3[j] = s3;
        tmax = fmaxf(tmax, fmaxf(fmaxf(s0, s1), fmaxf(s2, s3)));
      }
      tmax = fmaxf(tmax, __shfl_xor(tmax, 16));
      tmax = fmaxf(tmax, __shfl_xor(tmax, 32));
      const float mnew = fmaxf(m, tmax);
      const float sc = __expf(m - mnew);
      float tsum = 0.f;
      #pragma unroll
      for (int j = 0; j < 4; ++j) {
        p0[j] = __expf(p0[j] - mnew);
        p1[j] = __expf(p1[j] - mnew);
        p2[j] = __expf(p2[j] - mnew);
        p3[j] = __expf(p3[j] - mnew);
        tsum += (p0[j] + p1[j]) + (p2[j] + p3[j]);
      }
      tsum += __shfl_xor(tsum, 16);
      tsum += __shfl_xor(tsum, 32);
      l = l * sc + tsum;
      m = mnew;
      bf16x8 pfa, pfb;
      #pragma unroll
      for (int j = 0; j < 4; ++j) {
        pfa[j] = (bf16)p0[j]; pfa[4 + j] = (bf16)p1[j];
        pfb[j] = (bf16)p2[j]; pfb[4 + j] = (bf16)p3[j];
      }
      #pragma unroll
      for (int j = 0; j < 4; ++j) {
        const float scj = __shfl(sc, 4*g + j);
        #pragma unroll
        for (int c = 0; c < 4; ++c) ov[c][j] *= scj;
      }
      #pragma unroll
      for (int c = 0; c < 4; ++c) {
        bf16x8 vfa = *(const bf16x8*)(Vb + (c*16 + r) * 32 + g * 8);
        bf16x8 vfb = *(const bf16x8*)(Vb + 2048 + (c*16 + r) * 32 + g * 8);
        ov[c] = mfma32(pfa, vfa, ov[c]);
        ov[c] = mfma32(pfb, vfb, ov[c]);
      }
      __syncthreads();
      cur ^= 1;
    }
    #pragma unroll
    for (int j = 0; j < 4; ++j) {
      const float lj = __shfl(l, 4*g + j);
      const float inv = 1.f / lj;
      const int row = b*SS + q0 + 4*g + j;
      #pragma unroll
      for (int c = 0; c < 4; ++c)
        ctx[(size_t)row * DD + h*HDIM + c*16 + r] = (bf16)(ov[c][j] * inv);
    }
  }
}

// ---------------- LayerNorm(a + p0 [+ p1 + colbias]) * g + b ----------------
template<int NP, int HASB, int WRITEB>
__global__ __launch_bounds__(256)
void ln_kernel(const float* __restrict__ a, const float* __restrict__ p0,
               const float* __restrict__ p1, const float* __restrict__ cb,
               const float* __restrict__ gam, const float* __restrict__ bet,
               float* __restrict__ outf, bf16* __restrict__ outb) {
  const int row = blockIdx.x;
  const int tid = threadIdx.x;
  const size_t base = (size_t)row * DD + tid * 4;
  float4 va = *(const float4*)(a + base);
  float4 vc = *(const float4*)(p0 + base);
  float x0 = va.x + vc.x, x1 = va.y + vc.y, x2 = va.z + vc.z, x3 = va.w + vc.w;
  if (NP > 1) {
    float4 vp = *(const float4*)(p1 + base);
    x0 += vp.x; x1 += vp.y; x2 += vp.z; x3 += vp.w;
  }
  if (HASB) {
    float4 vb4 = *(const float4*)(cb + tid * 4);
    x0 += vb4.x; x1 += vb4.y; x2 += vb4.z; x3 += vb4.w;
  }
  float s  = x0 + x1 + x2 + x3;
  float s2 = x0*x0 + x1*x1 + x2*x2 + x3*x3;
  #pragma unroll
  for (int off = 32; off > 0; off >>= 1) {
    s  += __shfl_xor(s,  off);
    s2 += __shfl_xor(s2, off);
  }
  __shared__ float red[8];
  const int wv = tid >> 6;
  if ((tid & 63) == 0) { red[wv] = s; red[wv + 4] = s2; }
  __syncthreads();
  s  = red[0] + red[1] + red[2] + red[3];
  s2 = red[4] + red[5] + red[6] + red[7];
  const float mu  = s * (1.f / DD);
  const float var = s2 * (1.f / DD) - mu * mu;
  const float rs  = rsqrtf(var + 1e-5f);
  float4 vg = *(const float4*)(gam + tid * 4);
  float4 vb = *(const float4*)(bet + tid * 4);
  float y0 = (x0 - mu) * rs * vg.x + vb.x;
  float y1 = (x1 - mu) * rs * vg.y + vb.y;
  float y2 = (x2 - mu) * rs * vg.z + vb.z;
  float y3 = (x3 - mu) * rs * vg.w + vb.w;
  float4 yo; yo.x = y0; yo.y = y1; yo.z = y2; yo.w = y3;
  *(float4*)(outf + base) = yo;
  if (WRITEB) {
    bf16x4 ob;
    ob[0] = (bf16)y0; ob[1] = (bf16)y1; ob[2] = (bf16)y2; ob[3] = (bf16)y3;
    *(bf16x4*)(outb + base) = ob;
  }
}

extern "C" void kernel_launch(void* const* d_in, const int* in_sizes, int n_in,
                              void* d_out, int out_size, void* d_ws, size_t ws_size,
                              hipStream_t stream) {
  const float* src  = (const float*)d_in[0];
  const float* Wq   = (const float*)d_in[2];
  const float* bq   = (const float*)d_in[3];
  const float* Wk   = (const float*)d_in[4];
  const float* bk   = (const float*)d_in[5];
  const float* Wv   = (const float*)d_in[6];
  const float* bv   = (const float*)d_in[7];
  const float* Wo   = (const float*)d_in[8];
  const float* bo   = (const float*)d_in[9];
  const float* W1   = (const float*)d_in[10];
  const float* b1   = (const float*)d_in[11];
  const float* W2   = (const float*)d_in[12];
  const float* b2   = (const float*)d_in[13];
  const float* ln1g = (const float*)d_in[14];
  const float* ln1b = (const float*)d_in[15];
  const float* ln2g = (const float*)d_in[16];
  const float* ln2b = (const float*)d_in[17];

  char* ws = (char*)d_ws;
  const size_t MB = 1024 * 1024;
  bf16* wqkvt = (bf16*)(ws + 0 * MB);    // [3072][1024] bf16 = 6MB (dead after QKV)
  bf16* wot   = (bf16*)(ws + 6 * MB);    // 2MB (dead after Wo)
  bf16* w1t   = (bf16*)(ws + 8 * MB);    // 8MB (dead after FF1)
  bf16* w2t   = (bf16*)(ws + 16 * MB);   // 8MB
  bf16* bsrc  = (bf16*)(ws + 24 * MB);   // 8MB; reused as xb
  bf16* xb    = bsrc;
  bf16* qkv   = (bf16*)(ws + 32 * MB);   // [4096][3072] = 24MB
  bf16* vt    = (bf16*)(ws + 56 * MB);   // 8MB
  bf16* ctx   = (bf16*)(ws + 64 * MB);   // 8MB
  bf16* ff1   = qkv;                     // [4096][4096] = 32MB, reuses qkv+vt
  float* xf   = (float*)(ws + 72 * MB);  // 16MB
  float* bqkv = (float*)(ws + 88 * MB);  // 12KB
  float* ff2p1 = (float*)(ws + 0 * MB);  // 16MB partial over dead wqkvt/wot/w1t
  float* attn_out = (float*)d_out;       // fp32 scratch in d_out
  float* ff2p0 = (float*)d_out;
  float* outp  = (float*)d_out;

  // conversions
  cvt_bf16_kernel<<<(MR * DD) / 1024, 256, 0, stream>>>(src, bsrc, MR * DD);
  transpose_w_kernel<<<dim3(32, 32), 256, 0, stream>>>(Wq, wqkvt,             DD, DD);
  transpose_w_kernel<<<dim3(32, 32), 256, 0, stream>>>(Wk, wqkvt + 1024*1024, DD, DD);
  transpose_w_kernel<<<dim3(32, 32), 256, 0, stream>>>(Wv, wqkvt + 2048*1024, DD, DD);
  transpose_w_kernel<<<dim3(32, 32), 256, 0, stream>>>(Wo, wot, DD, DD);
  transpose_w_kernel<<<dim3(128, 32), 256, 0, stream>>>(W1, w1t, DD, FFD);
  transpose_w_kernel<<<dim3(32, 128), 256, 0, stream>>>(W2, w2t, FFD, DD);
  concat_bias_kernel<<<12, 256, 0, stream>>>(bq, bk, bv, bqkv);

  // fused QKV projection: [4096,1024] @ [1024,3072] -> [4096,3072] (256^2 pipelined)
  gemm256<1, 0><<<dim3(QKVLD / 256, MR / 256), 512, 0, stream>>>(bsrc, wqkvt, bqkv, qkv, QKVLD, DD);
  transpose_v_kernel<<<dim3(SS / 32, HDIM / 32, BB * HH), 256, 0, stream>>>(qkv + 2048, vt);

  // attention (Q at col 0, K at col 1024 of qkv)
  attn_kernel<<<dim3(16, BB * HH), 256, 0, stream>>>(qkv, qkv + 1024, vt, ctx);

  // output projection + LN1
  gemm_bt<0, 0, 1><<<dim3(8, 32), 256, 0, stream>>>(ctx, wot, bo, attn_out, nullptr, MR, DD, DD);
  ln_kernel<1, 0, 1><<<MR, 256, 0, stream>>>(src, attn_out, nullptr, nullptr, ln1g, ln1b, xf, xb);

  // FFN: FF1 256^2 pipelined; FF2 split-K=2 (partials: d_out + ws0), reduce fused in LN2
  gemm256<1, 1><<<dim3(FFD / 256, MR / 256), 512, 0, stream>>>(xb, w1t, b1, ff1, FFD, DD);
  gemm_bt<0, 0, 2><<<dim3(8, 32, 2), 256, 0, stream>>>(ff1, w2t, nullptr, ff2p0, ff2p1, MR, DD, FFD);
  ln_kernel<2, 1, 0><<<MR, 256, 0, stream>>>(xf, ff2p0, ff2p1, b2, ln2g, ln2b, outp, (bf16*)nullptr);
}

// Round 6
// 269.742 us; speedup vs baseline: 1.9465x; 1.0310x over previous
//
#include <hip/hip_runtime.h>

#define SS 2048
#define DD 1024
#define HH 16
#define HDIM 64
#define BB 2
#define FFD 4096
#define MR (BB*SS)   // 4096 rows
#define QKVLD 3072   // fused qkv row stride

typedef __bf16 bf16;
typedef __bf16 bf16x4 __attribute__((ext_vector_type(4)));
typedef __bf16 bf16x8 __attribute__((ext_vector_type(8)));
typedef float f32x4 __attribute__((ext_vector_type(4)));

__device__ inline f32x4 mfma32(bf16x8 a, bf16x8 b, f32x4 c) {
  return __builtin_amdgcn_mfma_f32_16x16x32_bf16(a, b, c, 0, 0, 0);
}

__device__ inline void gload_lds16(const void* g, void* l) {
  __builtin_amdgcn_global_load_lds(
      (const __attribute__((address_space(1))) void*)g,
      (__attribute__((address_space(3))) void*)l, 16, 0, 0);
}

// ---------------- fp32 -> bf16 elementwise ----------------
__global__ __launch_bounds__(256)
void cvt_bf16_kernel(const float* __restrict__ in, bf16* __restrict__ out, int n) {
  int i = (blockIdx.x * 256 + threadIdx.x) * 4;
  if (i >= n) return;
  float4 v = *(const float4*)(in + i);
  bf16x4 o;
  o[0] = (bf16)v.x; o[1] = (bf16)v.y; o[2] = (bf16)v.z; o[3] = (bf16)v.w;
  *(bf16x4*)(out + i) = o;
}

// ---------------- concat bias qkv ----------------
__global__ __launch_bounds__(256)
void concat_bias_kernel(const float* __restrict__ bq, const float* __restrict__ bk,
                        const float* __restrict__ bv, float* __restrict__ out) {
  int i = blockIdx.x * 256 + threadIdx.x;
  out[i] = i < 1024 ? bq[i] : (i < 2048 ? bk[i - 1024] : bv[i - 2048]);
}

// ---------------- W [K,N] fp32 -> Wt [N,K] bf16 ----------------
__global__ __launch_bounds__(256)
void transpose_w_kernel(const float* __restrict__ W, bf16* __restrict__ Wt,
                        int K, int N) {
  __shared__ float t[32][33];
  int tx = threadIdx.x & 31, ty = threadIdx.x >> 5;  // 32 x 8
  int n0 = blockIdx.x * 32, k0 = blockIdx.y * 32;
  #pragma unroll
  for (int i = 0; i < 4; ++i)
    t[ty + i*8][tx] = W[(size_t)(k0 + ty + i*8) * N + n0 + tx];
  __syncthreads();
  #pragma unroll
  for (int i = 0; i < 4; ++i)
    Wt[(size_t)(n0 + ty + i*8) * K + k0 + tx] = (bf16)t[tx][ty + i*8];
}

// ---------------- V (cols of qkv2d) -> Vt [B,H,HD,S] bf16 ----------------
__global__ __launch_bounds__(256)
void transpose_v_kernel(const bf16* __restrict__ V2d, bf16* __restrict__ Vt) {
  __shared__ bf16 t[32][33];
  int tx = threadIdx.x & 31, ty = threadIdx.x >> 5;
  int s0 = blockIdx.x * 32, d0 = blockIdx.y * 32;
  int bh = blockIdx.z;
  int b = bh >> 4, h = bh & 15;
  #pragma unroll
  for (int i = 0; i < 4; ++i)
    t[ty + i*8][tx] = V2d[(size_t)(b*SS + s0 + ty + i*8) * QKVLD + h*HDIM + d0 + tx];
  __syncthreads();
  #pragma unroll
  for (int i = 0; i < 4; ++i)
    Vt[((size_t)bh*HDIM + d0 + ty + i*8) * SS + s0 + tx] = t[tx][ty + i*8];
}

// ======== 256x256 deep-pipelined GEMM: C[M,N] = A[M,K] @ Bt[N,K]^T + bias ========
template<int OUT_BF16, int RELU>
__global__ __launch_bounds__(512)
void gemm256(const bf16* __restrict__ A, const bf16* __restrict__ Bt,
             const float* __restrict__ bias, void* __restrict__ Cout,
             int Ndim, int Kdim) {
  __shared__ bf16 Asm[2][256 * 64];
  __shared__ bf16 Bsm[2][256 * 64];
  const int gx = gridDim.x;
  const int nwg = gx * gridDim.y;
  const int lin = blockIdx.y * gx + blockIdx.x;
  const int swz = (lin & 7) * (nwg >> 3) + (lin >> 3);
  const int by = swz / gx, bx = swz - by * gx;
  const int m0 = by * 256, n0 = bx * 256;
  const int tid = threadIdx.x;
  const int wave = tid >> 6, lane = tid & 63;
  const int g = lane >> 4, r = lane & 15;
  const int wr = wave >> 2, wn = wave & 3;

  const int srow = wave * 8 + (lane >> 3);
  const int skslot = (lane & 7) ^ (lane >> 3);
  const bf16* Ag = A + (size_t)(m0 + srow) * Kdim + skslot * 8;
  const bf16* Bg = Bt + (size_t)(n0 + srow) * Kdim + skslot * 8;

  f32x4 acc[8][4] = {};
  const int NT = Kdim >> 6;

  auto stage = [&](int t) {
    const int kb = t << 6;
    bf16* Ad = Asm[t & 1];
    bf16* Bd = Bsm[t & 1];
    #pragma unroll
    for (int j = 0; j < 4; ++j)
      gload_lds16(Ag + (size_t)j * 64 * Kdim + kb, Ad + (j * 64 + wave * 8) * 64);
    #pragma unroll
    for (int j = 0; j < 4; ++j)
      gload_lds16(Bg + (size_t)j * 64 * Kdim + kb, Bd + (j * 64 + wave * 8) * 64);
  };

  stage(0);
  asm volatile("s_waitcnt vmcnt(0)" ::: "memory");
  asm volatile("s_barrier" ::: "memory");

  for (int t = 0; t < NT; ++t) {
    const bf16* Ab = Asm[t & 1];
    const bf16* Bb = Bsm[t & 1];
    #pragma unroll
    for (int ph = 0; ph < 4; ++ph) {
      const int mq = ph >> 1, nq = ph & 1;
      bf16x8 af[4][2], bfr[2][2];
      #pragma unroll
      for (int i = 0; i < 4; ++i) {
        const int row = wr * 128 + (mq * 4 + i) * 16 + r;
        #pragma unroll
        for (int kk = 0; kk < 2; ++kk)
          af[i][kk] = *(const bf16x8*)(Ab + row * 64 + (((kk * 4 + g) ^ (r & 7)) * 8));
      }
      #pragma unroll
      for (int i = 0; i < 2; ++i) {
        const int rowb = wn * 64 + (nq * 2 + i) * 16 + r;
        #pragma unroll
        for (int kk = 0; kk < 2; ++kk)
          bfr[i][kk] = *(const bf16x8*)(Bb + rowb * 64 + (((kk * 4 + g) ^ (r & 7)) * 8));
      }
      if (ph == 0 && t + 1 < NT) stage(t + 1);
      asm volatile("s_barrier" ::: "memory");
      __builtin_amdgcn_s_setprio(1);
      #pragma unroll
      for (int i = 0; i < 4; ++i)
        #pragma unroll
        for (int jn = 0; jn < 2; ++jn)
          #pragma unroll
          for (int kk = 0; kk < 2; ++kk)
            acc[mq * 4 + i][nq * 2 + jn] =
                mfma32(af[i][kk], bfr[jn][kk], acc[mq * 4 + i][nq * 2 + jn]);
      __builtin_amdgcn_s_setprio(0);
      asm volatile("s_barrier" ::: "memory");
    }
    asm volatile("s_waitcnt vmcnt(0)" ::: "memory");
    asm volatile("s_barrier" ::: "memory");
  }

  #pragma unroll
  for (int mi = 0; mi < 8; ++mi) {
    #pragma unroll
    for (int ni = 0; ni < 4; ++ni) {
      const int col = n0 + wn * 64 + ni * 16 + r;
      const float bv = bias[col];
      #pragma unroll
      for (int jj = 0; jj < 4; ++jj) {
        const int row = m0 + wr * 128 + mi * 16 + g * 4 + jj;
        float v = acc[mi][ni][jj] + bv;
        if (RELU) v = fmaxf(v, 0.f);
        if (OUT_BF16) ((bf16*)Cout)[(size_t)row * Ndim + col] = (bf16)v;
        else          ((float*)Cout)[(size_t)row * Ndim + col] = v;
      }
    }
  }
}

// ---------------- GEMM 128^2 (m97 structure): used for Wo + FF2 split-K ----------------
template<int OUT_BF16, int RELU, int SPLITK>
__global__ __launch_bounds__(256)
void gemm_bt(const bf16* __restrict__ A, const bf16* __restrict__ Bt,
             const float* __restrict__ bias, void* __restrict__ Cout,
             float* __restrict__ Cout2, int Mdim, int Ndim, int Kdim) {
  __shared__ bf16 As[128 * 32];
  __shared__ bf16 Bs[128 * 32];
  const int gx = gridDim.x, gy = gridDim.y;
  const int nwg = gx * gy * gridDim.z;
  const int lin = (blockIdx.z * gy + blockIdx.y) * gx + blockIdx.x;
  const int swz = (lin & 7) * (nwg >> 3) + (lin >> 3);
  const int bz = swz / (gx * gy);
  const int rem = swz - bz * gx * gy;
  const int by = rem / gx;
  const int bx = rem - by * gx;
  const int tid = threadIdx.x;
  const int wave = tid >> 6;
  const int lane = tid & 63;
  const int g = lane >> 4;
  const int r = lane & 15;
  const int m0 = by * 128;
  const int n0 = bx * 128;
  const int kchunk = Kdim / SPLITK;
  const int kstart = bz * kchunk;
  const int wr = wave >> 1, wc = wave & 1;   // 2x2 waves -> 64x64 each
  f32x4 acc[4][4] = {};
  const int strow = tid >> 2;        // 0..63
  const int stcol = (tid & 3) * 8;
  const bf16* Abase = A + (size_t)(m0 + strow) * Kdim + kstart + stcol;
  const bf16* Bbase = Bt + (size_t)(n0 + strow) * Kdim + kstart + stcol;
  bf16* AsW = As + wave * 512;
  bf16* BsW = Bs + wave * 512;
  for (int k0 = 0; k0 < kchunk; k0 += 32) {
    __syncthreads();
    gload_lds16(Abase + k0, AsW);
    gload_lds16(Abase + k0 + (size_t)64 * Kdim, AsW + 2048);
    gload_lds16(Bbase + k0, BsW);
    gload_lds16(Bbase + k0 + (size_t)64 * Kdim, BsW + 2048);
    __syncthreads();
    bf16x8 af[4], bfr[4];
    #pragma unroll
    for (int i = 0; i < 4; ++i)
      af[i] = *(const bf16x8*)(As + (wr*64 + i*16 + r) * 32 + g * 8);
    #pragma unroll
    for (int i = 0; i < 4; ++i)
      bfr[i] = *(const bf16x8*)(Bs + (wc*64 + i*16 + r) * 32 + g * 8);
    #pragma unroll
    for (int mi = 0; mi < 4; ++mi)
      #pragma unroll
      for (int ni = 0; ni < 4; ++ni)
        acc[mi][ni] = mfma32(af[mi], bfr[ni], acc[mi][ni]);
  }
  float* outp = (SPLITK > 1 && bz) ? Cout2 : (float*)Cout;
  #pragma unroll
  for (int mi = 0; mi < 4; ++mi) {
    #pragma unroll
    for (int ni = 0; ni < 4; ++ni) {
      const int col = n0 + wc*64 + ni*16 + r;
      const float bv = (SPLITK > 1) ? 0.f : bias[col];
      #pragma unroll
      for (int j = 0; j < 4; ++j) {
        const int row = m0 + wr*64 + mi*16 + g*4 + j;
        float v = acc[mi][ni][j] + bv;
        if (RELU) v = fmaxf(v, 0.f);
        if (OUT_BF16) ((bf16*)Cout)[(size_t)row * Ndim + col] = (bf16)v;
        else          outp[(size_t)row * Ndim + col] = v;
      }
    }
  }
}

// ---------------- flash attention: LDS-staged K/V, XCD-local, slot-swizzled ----------------
// XCD remap: swz=(lin&7)*64+lin>>3, bh=swz>>4 -> each XCD owns 4 complete heads
// (K/V fetched by exactly one XCD L2). LDS slot swizzle (T2, both-sides):
// phys_slot = s ^ ((row>>1)&3); staging pre-swizzles the GLOBAL source
// (logical slot = (lane&3)^((lane>>3)&3), since staging row = 16w+(lane>>2)),
// reads apply the same XOR. V fragment reads become conflict-free; K halved.
__global__ __launch_bounds__(256)
void attn_kernel(const bf16* __restrict__ Q2d, const bf16* __restrict__ K2d,
                 const bf16* __restrict__ Vt, bf16* __restrict__ ctx) {
  __shared__ bf16 Ks[2 * 4096];   // 2 bufs x [2 halves][64][32]
  __shared__ bf16 Vs[2 * 4096];
  const int tid = threadIdx.x;
  const int wave = tid >> 6;
  const int lane = tid & 63;
  const int g = lane >> 4, r = lane & 15;
  const int lin = blockIdx.y * gridDim.x + blockIdx.x;   // 0..511
  const int swz = (lin & 7) * 64 + (lin >> 3);
  const int p = swz & 15;            // pair index 0..15
  const int bh = swz >> 4;           // 0..31
  const int b = bh >> 4, h = bh & 15;

  const int strow = wave * 16 + (lane >> 2);              // 0..63
  const int lslot = (lane & 3) ^ ((lane >> 3) & 3);       // pre-swizzled global slot
  const bf16* srcK0 = K2d + (size_t)(b*SS + strow) * QKVLD + h*HDIM + lslot * 8;
  const bf16* srcK1 = srcK0 + 32;
  const bf16* srcV0 = Vt + ((size_t)bh*HDIM + strow) * SS + lslot * 8;
  const bf16* srcV1 = srcV0 + 32;

  // swizzled LDS element offset for logical (row, slot s)
  auto sw = [](int row, int s) { return row * 32 + ((s ^ ((row >> 1) & 3)) * 8); };

  const int kr0 = 8 * (r >> 2) + (r & 3);      // permuted K row for S^T frag
  const int oKa0 = sw(kr0,      g), oKb0 = 2048 + oKa0;
  const int oKa1 = sw(kr0 +  4, g), oKb1 = 2048 + oKa1;
  const int oKa2 = sw(kr0 + 32, g), oKb2 = 2048 + oKa2;
  const int oKa3 = sw(kr0 + 36, g), oKb3 = 2048 + oKa3;
  int oV[4];
  #pragma unroll
  for (int c = 0; c < 4; ++c) oV[c] = sw(c * 16 + r, g);

  #pragma unroll
  for (int tt = 0; tt < 2; ++tt) {
    const int tile = tt ? (31 - p) : p;
    const int q0 = tile * 64 + wave * 16;
    const int qg = q0 + r;
    const bf16* qp = Q2d + (size_t)(b*SS + q0 + r) * QKVLD + h * HDIM;
    const bf16x8 qf0 = *(const bf16x8*)(qp + g * 8);
    const bf16x8 qf1 = *(const bf16x8*)(qp + 32 + g * 8);
    f32x4 ov[4] = {};
    float m = -3.0e38f, l = 0.f;
    const int nst = tile + 1;
    {
      bf16* kb = Ks + wave * 512;
      bf16* vb = Vs + wave * 512;
      gload_lds16(srcK0, kb);
      gload_lds16(srcK1, kb + 2048);
      gload_lds16(srcV0, vb);
      gload_lds16(srcV1, vb + 2048);
    }
    __syncthreads();
    int cur = 0;
    for (int st = 0; st < nst; ++st) {
      const int k0 = st * 64;
      if (st + 1 < nst) {
        const int kn = k0 + 64;
        bf16* kb = Ks + (cur ^ 1) * 4096 + wave * 512;
        bf16* vb = Vs + (cur ^ 1) * 4096 + wave * 512;
        gload_lds16(srcK0 + (size_t)kn * QKVLD, kb);
        gload_lds16(srcK1 + (size_t)kn * QKVLD, kb + 2048);
        gload_lds16(srcV0 + kn, vb);
        gload_lds16(srcV1 + kn, vb + 2048);
      }
      const bf16* Kb = Ks + cur * 4096;
      const bf16* Vb = Vs + cur * 4096;
      f32x4 c0 = {}, c1 = {}, c2 = {}, c3 = {};
      __builtin_amdgcn_s_setprio(1);
      c0 = mfma32(*(const bf16x8*)(Kb + oKa0), qf0, c0);
      c1 = mfma32(*(const bf16x8*)(Kb + oKa1), qf0, c1);
      c2 = mfma32(*(const bf16x8*)(Kb + oKa2), qf0, c2);
      c3 = mfma32(*(const bf16x8*)(Kb + oKa3), qf0, c3);
      c0 = mfma32(*(const bf16x8*)(Kb + oKb0), qf1, c0);
      c1 = mfma32(*(const bf16x8*)(Kb + oKb1), qf1, c1);
      c2 = mfma32(*(const bf16x8*)(Kb + oKb2), qf1, c2);
      c3 = mfma32(*(const bf16x8*)(Kb + oKb3), qf1, c3);
      __builtin_amdgcn_s_setprio(0);
      float p0[4], p1[4], p2[4], p3[4];
      float tmax = -3.0e38f;
      const bool need_mask = (k0 + 63 > qg);
      #pragma unroll
      for (int j = 0; j < 4; ++j) {
        float s0 = c0[j] * 0.125f;
        float s1 = c1[j] * 0.125f;
        float s2 = c2[j] * 0.125f;
        float s3 = c3[j] * 0.125f;
        if (need_mask) {
          if (k0 + 8*g + j > qg)          s0 = -3.0e38f;
          if (k0 + 8*g + 4 + j > qg)      s1 = -3.0e38f;
          if (k0 + 32 + 8*g + j > qg)     s2 = -3.0e38f;
          if (k0 + 32 + 8*g + 4 + j > qg) s3 = -3.0e38f;
        }
        p0[j] = s0; p1[j] = s1; p2[j] = s2; p3[j] = s3;
        tmax = fmaxf(tmax, fmaxf(fmaxf(s0, s1), fmaxf(s2, s3)));
      }
      tmax = fmaxf(tmax, __shfl_xor(tmax, 16));
      tmax = fmaxf(tmax, __shfl_xor(tmax, 32));
      const float mnew = fmaxf(m, tmax);
      const float sc = __expf(m - mnew);
      float tsum = 0.f;
      #pragma unroll
      for (int j = 0; j < 4; ++j) {
        p0[j] = __expf(p0[j] - mnew);
        p1[j] = __expf(p1[j] - mnew);
        p2[j] = __expf(p2[j] - mnew);
        p3[j] = __expf(p3[j] - mnew);
        tsum += (p0[j] + p1[j]) + (p2[j] + p3[j]);
      }
      tsum += __shfl_xor(tsum, 16);
      tsum += __shfl_xor(tsum, 32);
      l = l * sc + tsum;
      m = mnew;
      bf16x8 pfa, pfb;
      #pragma unroll
      for (int j = 0; j < 4; ++j) {
        pfa[j] = (bf16)p0[j]; pfa[4 + j] = (bf16)p1[j];
        pfb[j] = (bf16)p2[j]; pfb[4 + j] = (bf16)p3[j];
      }
      #pragma unroll
      for (int j = 0; j < 4; ++j) {
        const float scj = __shfl(sc, 4*g + j);
        #pragma unroll
        for (int c = 0; c < 4; ++c) ov[c][j] *= scj;
      }
      __builtin_amdgcn_s_setprio(1);
      #pragma unroll
      for (int c = 0; c < 4; ++c) {
        bf16x8 vfa = *(const bf16x8*)(Vb + oV[c]);
        bf16x8 vfb = *(const bf16x8*)(Vb + 2048 + oV[c]);
        ov[c] = mfma32(pfa, vfa, ov[c]);
        ov[c] = mfma32(pfb, vfb, ov[c]);
      }
      __builtin_amdgcn_s_setprio(0);
      __syncthreads();
      cur ^= 1;
    }
    #pragma unroll
    for (int j = 0; j < 4; ++j) {
      const float lj = __shfl(l, 4*g + j);
      const float inv = 1.f / lj;
      const int row = b*SS + q0 + 4*g + j;
      #pragma unroll
      for (int c = 0; c < 4; ++c)
        ctx[(size_t)row * DD + h*HDIM + c*16 + r] = (bf16)(ov[c][j] * inv);
    }
  }
}

// ---------------- LayerNorm(a + p0 [+ p1 + colbias]) * g + b ----------------
template<int NP, int HASB, int WRITEB>
__global__ __launch_bounds__(256)
void ln_kernel(const float* __restrict__ a, const float* __restrict__ p0,
               const float* __restrict__ p1, const float* __restrict__ cb,
               const float* __restrict__ gam, const float* __restrict__ bet,
               float* __restrict__ outf, bf16* __restrict__ outb) {
  const int row = blockIdx.x;
  const int tid = threadIdx.x;
  const size_t base = (size_t)row * DD + tid * 4;
  float4 va = *(const float4*)(a + base);
  float4 vc = *(const float4*)(p0 + base);
  float x0 = va.x + vc.x, x1 = va.y + vc.y, x2 = va.z + vc.z, x3 = va.w + vc.w;
  if (NP > 1) {
    float4 vp = *(const float4*)(p1 + base);
    x0 += vp.x; x1 += vp.y; x2 += vp.z; x3 += vp.w;
  }
  if (HASB) {
    float4 vb4 = *(const float4*)(cb + tid * 4);
    x0 += vb4.x; x1 += vb4.y; x2 += vb4.z; x3 += vb4.w;
  }
  float s  = x0 + x1 + x2 + x3;
  float s2 = x0*x0 + x1*x1 + x2*x2 + x3*x3;
  #pragma unroll
  for (int off = 32; off > 0; off >>= 1) {
    s  += __shfl_xor(s,  off);
    s2 += __shfl_xor(s2, off);
  }
  __shared__ float red[8];
  const int wv = tid >> 6;
  if ((tid & 63) == 0) { red[wv] = s; red[wv + 4] = s2; }
  __syncthreads();
  s  = red[0] + red[1] + red[2] + red[3];
  s2 = red[4] + red[5] + red[6] + red[7];
  const float mu  = s * (1.f / DD);
  const float var = s2 * (1.f / DD) - mu * mu;
  const float rs  = rsqrtf(var + 1e-5f);
  float4 vg = *(const float4*)(gam + tid * 4);
  float4 vb = *(const float4*)(bet + tid * 4);
  float y0 = (x0 - mu) * rs * vg.x + vb.x;
  float y1 = (x1 - mu) * rs * vg.y + vb.y;
  float y2 = (x2 - mu) * rs * vg.z + vb.z;
  float y3 = (x3 - mu) * rs * vg.w + vb.w;
  float4 yo; yo.x = y0; yo.y = y1; yo.z = y2; yo.w = y3;
  *(float4*)(outf + base) = yo;
  if (WRITEB) {
    bf16x4 ob;
    ob[0] = (bf16)y0; ob[1] = (bf16)y1; ob[2] = (bf16)y2; ob[3] = (bf16)y3;
    *(bf16x4*)(outb + base) = ob;
  }
}

extern "C" void kernel_launch(void* const* d_in, const int* in_sizes, int n_in,
                              void* d_out, int out_size, void* d_ws, size_t ws_size,
                              hipStream_t stream) {
  const float* src  = (const float*)d_in[0];
  const float* Wq   = (const float*)d_in[2];
  const float* bq   = (const float*)d_in[3];
  const float* Wk   = (const float*)d_in[4];
  const float* bk   = (const float*)d_in[5];
  const float* Wv   = (const float*)d_in[6];
  const float* bv   = (const float*)d_in[7];
  const float* Wo   = (const float*)d_in[8];
  const float* bo   = (const float*)d_in[9];
  const float* W1   = (const float*)d_in[10];
  const float* b1   = (const float*)d_in[11];
  const float* W2   = (const float*)d_in[12];
  const float* b2   = (const float*)d_in[13];
  const float* ln1g = (const float*)d_in[14];
  const float* ln1b = (const float*)d_in[15];
  const float* ln2g = (const float*)d_in[16];
  const float* ln2b = (const float*)d_in[17];

  char* ws = (char*)d_ws;
  const size_t MB = 1024 * 1024;
  bf16* wqkvt = (bf16*)(ws + 0 * MB);    // [3072][1024] bf16 = 6MB (dead after QKV)
  bf16* wot   = (bf16*)(ws + 6 * MB);    // 2MB (dead after Wo)
  bf16* w1t   = (bf16*)(ws + 8 * MB);    // 8MB (dead after FF1)
  bf16* w2t   = (bf16*)(ws + 16 * MB);   // 8MB
  bf16* bsrc  = (bf16*)(ws + 24 * MB);   // 8MB; reused as xb
  bf16* xb    = bsrc;
  bf16* qkv   = (bf16*)(ws + 32 * MB);   // [4096][3072] = 24MB
  bf16* vt    = (bf16*)(ws + 56 * MB);   // 8MB
  bf16* ctx   = (bf16*)(ws + 64 * MB);   // 8MB
  bf16* ff1   = qkv;                     // [4096][4096] = 32MB, reuses qkv+vt
  float* xf   = (float*)(ws + 72 * MB);  // 16MB
  float* bqkv = (float*)(ws + 88 * MB);  // 12KB
  float* ff2p1 = (float*)(ws + 0 * MB);  // 16MB partial over dead wqkvt/wot/w1t
  float* attn_out = (float*)d_out;       // fp32 scratch in d_out
  float* ff2p0 = (float*)d_out;
  float* outp  = (float*)d_out;

  // conversions
  cvt_bf16_kernel<<<(MR * DD) / 1024, 256, 0, stream>>>(src, bsrc, MR * DD);
  transpose_w_kernel<<<dim3(32, 32), 256, 0, stream>>>(Wq, wqkvt,             DD, DD);
  transpose_w_kernel<<<dim3(32, 32), 256, 0, stream>>>(Wk, wqkvt + 1024*1024, DD, DD);
  transpose_w_kernel<<<dim3(32, 32), 256, 0, stream>>>(Wv, wqkvt + 2048*1024, DD, DD);
  transpose_w_kernel<<<dim3(32, 32), 256, 0, stream>>>(Wo, wot, DD, DD);
  transpose_w_kernel<<<dim3(128, 32), 256, 0, stream>>>(W1, w1t, DD, FFD);
  transpose_w_kernel<<<dim3(32, 128), 256, 0, stream>>>(W2, w2t, FFD, DD);
  concat_bias_kernel<<<12, 256, 0, stream>>>(bq, bk, bv, bqkv);

  // fused QKV projection: [4096,1024] @ [1024,3072] -> [4096,3072] (256^2 pipelined)
  gemm256<1, 0><<<dim3(QKVLD / 256, MR / 256), 512, 0, stream>>>(bsrc, wqkvt, bqkv, qkv, QKVLD, DD);
  transpose_v_kernel<<<dim3(SS / 32, HDIM / 32, BB * HH), 256, 0, stream>>>(qkv + 2048, vt);

  // attention (Q at col 0, K at col 1024 of qkv)
  attn_kernel<<<dim3(16, BB * HH), 256, 0, stream>>>(qkv, qkv + 1024, vt, ctx);

  // output projection + LN1
  gemm_bt<0, 0, 1><<<dim3(8, 32), 256, 0, stream>>>(ctx, wot, bo, attn_out, nullptr, MR, DD, DD);
  ln_kernel<1, 0, 1><<<MR, 256, 0, stream>>>(src, attn_out, nullptr, nullptr, ln1g, ln1b, xf, xb);

  // FFN: FF1 256^2 pipelined; FF2 split-K=2 (partials: d_out + ws0), reduce fused in LN2
  gemm256<1, 1><<<dim3(FFD / 256, MR / 256), 512, 0, stream>>>(xb, w1t, b1, ff1, FFD, DD);
  gemm_bt<0, 0, 2><<<dim3(8, 32, 2), 256, 0, stream>>>(ff1, w2t, nullptr, ff2p0, ff2p1, MR, DD, FFD);
  ln_kernel<2, 1, 0><<<MR, 256, 0, stream>>>(xf, ff2p0, ff2p1, b2, ln2g, ln2b, outp, (bf16*)nullptr);
}

// Round 7
// 255.041 us; speedup vs baseline: 2.0587x; 1.0576x over previous
//
#include <hip/hip_runtime.h>

#define SS 2048
#define DD 1024
#define HH 16
#define HDIM 64
#define BB 2
#define FFD 4096
#define MR (BB*SS)   // 4096 rows
#define QKVLD 3072   // fused qkv row stride

typedef __bf16 bf16;
typedef __bf16 bf16x4 __attribute__((ext_vector_type(4)));
typedef __bf16 bf16x8 __attribute__((ext_vector_type(8)));
typedef float f32x4 __attribute__((ext_vector_type(4)));

struct P4 { bf16* p[4]; };

__device__ inline f32x4 mfma32(bf16x8 a, bf16x8 b, f32x4 c) {
  return __builtin_amdgcn_mfma_f32_16x16x32_bf16(a, b, c, 0, 0, 0);
}

__device__ inline void gload_lds16(const void* g, void* l) {
  __builtin_amdgcn_global_load_lds(
      (const __attribute__((address_space(1))) void*)g,
      (__attribute__((address_space(3))) void*)l, 16, 0, 0);
}

// ---------------- fp32 -> bf16 elementwise ----------------
__global__ __launch_bounds__(256)
void cvt_bf16_kernel(const float* __restrict__ in, bf16* __restrict__ out, int n) {
  int i = (blockIdx.x * 256 + threadIdx.x) * 4;
  if (i >= n) return;
  float4 v = *(const float4*)(in + i);
  bf16x4 o;
  o[0] = (bf16)v.x; o[1] = (bf16)v.y; o[2] = (bf16)v.z; o[3] = (bf16)v.w;
  *(bf16x4*)(out + i) = o;
}

// ---------------- concat bias qkv ----------------
__global__ __launch_bounds__(256)
void concat_bias_kernel(const float* __restrict__ bq, const float* __restrict__ bk,
                        const float* __restrict__ bv, float* __restrict__ out) {
  int i = blockIdx.x * 256 + threadIdx.x;
  out[i] = i < 1024 ? bq[i] : (i < 2048 ? bk[i - 1024] : bv[i - 2048]);
}

// ---------------- W [K,N] fp32 -> Wt [N,K] bf16 ----------------
__global__ __launch_bounds__(256)
void transpose_w_kernel(const float* __restrict__ W, bf16* __restrict__ Wt,
                        int K, int N) {
  __shared__ float t[32][33];
  int tx = threadIdx.x & 31, ty = threadIdx.x >> 5;  // 32 x 8
  int n0 = blockIdx.x * 32, k0 = blockIdx.y * 32;
  #pragma unroll
  for (int i = 0; i < 4; ++i)
    t[ty + i*8][tx] = W[(size_t)(k0 + ty + i*8) * N + n0 + tx];
  __syncthreads();
  #pragma unroll
  for (int i = 0; i < 4; ++i)
    Wt[(size_t)(n0 + ty + i*8) * K + k0 + tx] = (bf16)t[tx][ty + i*8];
}

// ---------------- V (cols of qkv2d) -> Vt [B,H,HD,S] bf16 ----------------
__global__ __launch_bounds__(256)
void transpose_v_kernel(const bf16* __restrict__ V2d, bf16* __restrict__ Vt) {
  __shared__ bf16 t[32][33];
  int tx = threadIdx.x & 31, ty = threadIdx.x >> 5;
  int s0 = blockIdx.x * 32, d0 = blockIdx.y * 32;
  int bh = blockIdx.z;
  int b = bh >> 4, h = bh & 15;
  #pragma unroll
  for (int i = 0; i < 4; ++i)
    t[ty + i*8][tx] = V2d[(size_t)(b*SS + s0 + ty + i*8) * QKVLD + h*HDIM + d0 + tx];
  __syncthreads();
  #pragma unroll
  for (int i = 0; i < 4; ++i)
    Vt[((size_t)bh*HDIM + d0 + ty + i*8) * SS + s0 + tx] = t[tx][ty + i*8];
}

// ======== 256x256 deep-pipelined GEMM ========
// SPLITK>1: blockIdx.z = K-chunk; bf16 partial (no bias/relu) to part.p[bz].
template<int OUT_BF16, int RELU, int SPLITK>
__global__ __launch_bounds__(512)
void gemm256(const bf16* __restrict__ A, const bf16* __restrict__ Bt,
             const float* __restrict__ bias, void* __restrict__ Cout,
             P4 part, int Ndim, int Kdim) {
  __shared__ bf16 Asm[2][256 * 64];
  __shared__ bf16 Bsm[2][256 * 64];
  const int gx = gridDim.x, gy = gridDim.y;
  const int gxy = gx * gy;
  const int nwg = gxy * gridDim.z;
  const int lin = (blockIdx.z * gy + blockIdx.y) * gx + blockIdx.x;
  const int swz = (lin & 7) * (nwg >> 3) + (lin >> 3);
  int bz = 0, rem = swz;
  if (SPLITK > 1) { bz = swz / gxy; rem = swz - bz * gxy; }
  const int by = rem / gx, bx = rem - by * gx;
  const int m0 = by * 256, n0 = bx * 256;
  const int tid = threadIdx.x;
  const int wave = tid >> 6, lane = tid & 63;
  const int g = lane >> 4, r = lane & 15;
  const int wr = wave >> 2, wn = wave & 3;
  const int kstart = bz * (Kdim / SPLITK);

  const int srow = wave * 8 + (lane >> 3);
  const int skslot = (lane & 7) ^ (lane >> 3);
  const bf16* Ag = A + (size_t)(m0 + srow) * Kdim + kstart + skslot * 8;
  const bf16* Bg = Bt + (size_t)(n0 + srow) * Kdim + kstart + skslot * 8;

  f32x4 acc[8][4] = {};
  const int NT = (Kdim / SPLITK) >> 6;

  auto stage = [&](int t) {
    const int kb = t << 6;
    bf16* Ad = Asm[t & 1];
    bf16* Bd = Bsm[t & 1];
    #pragma unroll
    for (int j = 0; j < 4; ++j)
      gload_lds16(Ag + (size_t)j * 64 * Kdim + kb, Ad + (j * 64 + wave * 8) * 64);
    #pragma unroll
    for (int j = 0; j < 4; ++j)
      gload_lds16(Bg + (size_t)j * 64 * Kdim + kb, Bd + (j * 64 + wave * 8) * 64);
  };

  stage(0);
  asm volatile("s_waitcnt vmcnt(0)" ::: "memory");
  asm volatile("s_barrier" ::: "memory");

  for (int t = 0; t < NT; ++t) {
    const bf16* Ab = Asm[t & 1];
    const bf16* Bb = Bsm[t & 1];
    #pragma unroll
    for (int ph = 0; ph < 4; ++ph) {
      const int mq = ph >> 1, nq = ph & 1;
      bf16x8 af[4][2], bfr[2][2];
      #pragma unroll
      for (int i = 0; i < 4; ++i) {
        const int row = wr * 128 + (mq * 4 + i) * 16 + r;
        #pragma unroll
        for (int kk = 0; kk < 2; ++kk)
          af[i][kk] = *(const bf16x8*)(Ab + row * 64 + (((kk * 4 + g) ^ (r & 7)) * 8));
      }
      #pragma unroll
      for (int i = 0; i < 2; ++i) {
        const int rowb = wn * 64 + (nq * 2 + i) * 16 + r;
        #pragma unroll
        for (int kk = 0; kk < 2; ++kk)
          bfr[i][kk] = *(const bf16x8*)(Bb + rowb * 64 + (((kk * 4 + g) ^ (r & 7)) * 8));
      }
      if (ph == 0 && t + 1 < NT) stage(t + 1);
      asm volatile("s_barrier" ::: "memory");
      __builtin_amdgcn_s_setprio(1);
      #pragma unroll
      for (int i = 0; i < 4; ++i)
        #pragma unroll
        for (int jn = 0; jn < 2; ++jn)
          #pragma unroll
          for (int kk = 0; kk < 2; ++kk)
            acc[mq * 4 + i][nq * 2 + jn] =
                mfma32(af[i][kk], bfr[jn][kk], acc[mq * 4 + i][nq * 2 + jn]);
      __builtin_amdgcn_s_setprio(0);
      asm volatile("s_barrier" ::: "memory");
    }
    asm volatile("s_waitcnt vmcnt(0)" ::: "memory");
    asm volatile("s_barrier" ::: "memory");
  }

  #pragma unroll
  for (int mi = 0; mi < 8; ++mi) {
    #pragma unroll
    for (int ni = 0; ni < 4; ++ni) {
      const int col = n0 + wn * 64 + ni * 16 + r;
      const float bv = (SPLITK > 1) ? 0.f : bias[col];
      #pragma unroll
      for (int jj = 0; jj < 4; ++jj) {
        const int row = m0 + wr * 128 + mi * 16 + g * 4 + jj;
        float v = acc[mi][ni][jj] + bv;
        if (RELU) v = fmaxf(v, 0.f);
        if (SPLITK > 1) part.p[bz][(size_t)row * Ndim + col] = (bf16)v;
        else if (OUT_BF16) ((bf16*)Cout)[(size_t)row * Ndim + col] = (bf16)v;
        else               ((float*)Cout)[(size_t)row * Ndim + col] = v;
      }
    }
  }
}

// ---------------- GEMM 128^2 (m97 structure): used for Wo split-K ----------------
template<int OUT_BF16, int RELU, int SPLITK>
__global__ __launch_bounds__(256)
void gemm_bt(const bf16* __restrict__ A, const bf16* __restrict__ Bt,
             const float* __restrict__ bias, void* __restrict__ Cout,
             float* __restrict__ Cout2, int Mdim, int Ndim, int Kdim) {
  __shared__ bf16 As[128 * 32];
  __shared__ bf16 Bs[128 * 32];
  const int gx = gridDim.x, gy = gridDim.y;
  const int nwg = gx * gy * gridDim.z;
  const int lin = (blockIdx.z * gy + blockIdx.y) * gx + blockIdx.x;
  const int swz = (lin & 7) * (nwg >> 3) + (lin >> 3);
  const int bz = swz / (gx * gy);
  const int rem = swz - bz * gx * gy;
  const int by = rem / gx;
  const int bx = rem - by * gx;
  const int tid = threadIdx.x;
  const int wave = tid >> 6;
  const int lane = tid & 63;
  const int g = lane >> 4;
  const int r = lane & 15;
  const int m0 = by * 128;
  const int n0 = bx * 128;
  const int kchunk = Kdim / SPLITK;
  const int kstart = bz * kchunk;
  const int wr = wave >> 1, wc = wave & 1;   // 2x2 waves -> 64x64 each
  f32x4 acc[4][4] = {};
  const int strow = tid >> 2;        // 0..63
  const int stcol = (tid & 3) * 8;
  const bf16* Abase = A + (size_t)(m0 + strow) * Kdim + kstart + stcol;
  const bf16* Bbase = Bt + (size_t)(n0 + strow) * Kdim + kstart + stcol;
  bf16* AsW = As + wave * 512;
  bf16* BsW = Bs + wave * 512;
  for (int k0 = 0; k0 < kchunk; k0 += 32) {
    __syncthreads();
    gload_lds16(Abase + k0, AsW);
    gload_lds16(Abase + k0 + (size_t)64 * Kdim, AsW + 2048);
    gload_lds16(Bbase + k0, BsW);
    gload_lds16(Bbase + k0 + (size_t)64 * Kdim, BsW + 2048);
    __syncthreads();
    bf16x8 af[4], bfr[4];
    #pragma unroll
    for (int i = 0; i < 4; ++i)
      af[i] = *(const bf16x8*)(As + (wr*64 + i*16 + r) * 32 + g * 8);
    #pragma unroll
    for (int i = 0; i < 4; ++i)
      bfr[i] = *(const bf16x8*)(Bs + (wc*64 + i*16 + r) * 32 + g * 8);
    #pragma unroll
    for (int mi = 0; mi < 4; ++mi)
      #pragma unroll
      for (int ni = 0; ni < 4; ++ni)
        acc[mi][ni] = mfma32(af[mi], bfr[ni], acc[mi][ni]);
  }
  float* outp = (SPLITK > 1 && bz) ? Cout2 : (float*)Cout;
  #pragma unroll
  for (int mi = 0; mi < 4; ++mi) {
    #pragma unroll
    for (int ni = 0; ni < 4; ++ni) {
      const int col = n0 + wc*64 + ni*16 + r;
      const float bv = (SPLITK > 1) ? 0.f : bias[col];
      #pragma unroll
      for (int j = 0; j < 4; ++j) {
        const int row = m0 + wr*64 + mi*16 + g*4 + j;
        float v = acc[mi][ni][j] + bv;
        if (RELU) v = fmaxf(v, 0.f);
        if (OUT_BF16) ((bf16*)Cout)[(size_t)row * Ndim + col] = (bf16)v;
        else          outp[(size_t)row * Ndim + col] = v;
      }
    }
  }
}

// ---------------- flash attention: LDS-staged K/V, XCD-local, slot-swizzled ----------------
__global__ __launch_bounds__(256)
void attn_kernel(const bf16* __restrict__ Q2d, const bf16* __restrict__ K2d,
                 const bf16* __restrict__ Vt, bf16* __restrict__ ctx) {
  __shared__ bf16 Ks[2 * 4096];   // 2 bufs x [2 halves][64][32]
  __shared__ bf16 Vs[2 * 4096];
  const int tid = threadIdx.x;
  const int wave = tid >> 6;
  const int lane = tid & 63;
  const int g = lane >> 4, r = lane & 15;
  const int lin = blockIdx.y * gridDim.x + blockIdx.x;   // 0..511
  const int swz = (lin & 7) * 64 + (lin >> 3);
  const int p = swz & 15;            // pair index 0..15
  const int bh = swz >> 4;           // 0..31
  const int b = bh >> 4, h = bh & 15;

  const int strow = wave * 16 + (lane >> 2);              // 0..63
  const int lslot = (lane & 3) ^ ((lane >> 3) & 3);       // pre-swizzled global slot
  const bf16* srcK0 = K2d + (size_t)(b*SS + strow) * QKVLD + h*HDIM + lslot * 8;
  const bf16* srcK1 = srcK0 + 32;
  const bf16* srcV0 = Vt + ((size_t)bh*HDIM + strow) * SS + lslot * 8;
  const bf16* srcV1 = srcV0 + 32;

  auto sw = [](int row, int s) { return row * 32 + ((s ^ ((row >> 1) & 3)) * 8); };

  const int kr0 = 8 * (r >> 2) + (r & 3);      // permuted K row for S^T frag
  const int oKa0 = sw(kr0,      g), oKb0 = 2048 + oKa0;
  const int oKa1 = sw(kr0 +  4, g), oKb1 = 2048 + oKa1;
  const int oKa2 = sw(kr0 + 32, g), oKb2 = 2048 + oKa2;
  const int oKa3 = sw(kr0 + 36, g), oKb3 = 2048 + oKa3;
  int oV[4];
  #pragma unroll
  for (int c = 0; c < 4; ++c) oV[c] = sw(c * 16 + r, g);

  #pragma unroll
  for (int tt = 0; tt < 2; ++tt) {
    const int tile = tt ? (31 - p) : p;
    const int q0 = tile * 64 + wave * 16;
    const int qg = q0 + r;
    const bf16* qp = Q2d + (size_t)(b*SS + q0 + r) * QKVLD + h * HDIM;
    const bf16x8 qf0 = *(const bf16x8*)(qp + g * 8);
    const bf16x8 qf1 = *(const bf16x8*)(qp + 32 + g * 8);
    f32x4 ov[4] = {};
    float m = -3.0e38f, l = 0.f;
    const int nst = tile + 1;
    {
      bf16* kb = Ks + wave * 512;
      bf16* vb = Vs + wave * 512;
      gload_lds16(srcK0, kb);
      gload_lds16(srcK1, kb + 2048);
      gload_lds16(srcV0, vb);
      gload_lds16(srcV1, vb + 2048);
    }
    __syncthreads();
    int cur = 0;
    for (int st = 0; st < nst; ++st) {
      const int k0 = st * 64;
      if (st + 1 < nst) {
        const int kn = k0 + 64;
        bf16* kb = Ks + (cur ^ 1) * 4096 + wave * 512;
        bf16* vb = Vs + (cur ^ 1) * 4096 + wave * 512;
        gload_lds16(srcK0 + (size_t)kn * QKVLD, kb);
        gload_lds16(srcK1 + (size_t)kn * QKVLD, kb + 2048);
        gload_lds16(srcV0 + kn, vb);
        gload_lds16(srcV1 + kn, vb + 2048);
      }
      const bf16* Kb = Ks + cur * 4096;
      const bf16* Vb = Vs + cur * 4096;
      f32x4 c0 = {}, c1 = {}, c2 = {}, c3 = {};
      __builtin_amdgcn_s_setprio(1);
      c0 = mfma32(*(const bf16x8*)(Kb + oKa0), qf0, c0);
      c1 = mfma32(*(const bf16x8*)(Kb + oKa1), qf0, c1);
      c2 = mfma32(*(const bf16x8*)(Kb + oKa2), qf0, c2);
      c3 = mfma32(*(const bf16x8*)(Kb + oKa3), qf0, c3);
      c0 = mfma32(*(const bf16x8*)(Kb + oKb0), qf1, c0);
      c1 = mfma32(*(const bf16x8*)(Kb + oKb1), qf1, c1);
      c2 = mfma32(*(const bf16x8*)(Kb + oKb2), qf1, c2);
      c3 = mfma32(*(const bf16x8*)(Kb + oKb3), qf1, c3);
      __builtin_amdgcn_s_setprio(0);
      float p0[4], p1[4], p2[4], p3[4];
      float tmax = -3.0e38f;
      const bool need_mask = (k0 + 63 > qg);
      #pragma unroll
      for (int j = 0; j < 4; ++j) {
        float s0 = c0[j] * 0.125f;
        float s1 = c1[j] * 0.125f;
        float s2 = c2[j] * 0.125f;
        float s3 = c3[j] * 0.125f;
        if (need_mask) {
          if (k0 + 8*g + j > qg)          s0 = -3.0e38f;
          if (k0 + 8*g + 4 + j > qg)      s1 = -3.0e38f;
          if (k0 + 32 + 8*g + j > qg)     s2 = -3.0e38f;
          if (k0 + 32 + 8*g + 4 + j > qg) s3 = -3.0e38f;
        }
        p0[j] = s0; p1[j] = s1; p2[j] = s2; p3[j] = s3;
        tmax = fmaxf(tmax, fmaxf(fmaxf(s0, s1), fmaxf(s2, s3)));
      }
      tmax = fmaxf(tmax, __shfl_xor(tmax, 16));
      tmax = fmaxf(tmax, __shfl_xor(tmax, 32));
      const float mnew = fmaxf(m, tmax);
      const float sc = __expf(m - mnew);
      float tsum = 0.f;
      #pragma unroll
      for (int j = 0; j < 4; ++j) {
        p0[j] = __expf(p0[j] - mnew);
        p1[j] = __expf(p1[j] - mnew);
        p2[j] = __expf(p2[j] - mnew);
        p3[j] = __expf(p3[j] - mnew);
        tsum += (p0[j] + p1[j]) + (p2[j] + p3[j]);
      }
      tsum += __shfl_xor(tsum, 16);
      tsum += __shfl_xor(tsum, 32);
      l = l * sc + tsum;
      m = mnew;
      bf16x8 pfa, pfb;
      #pragma unroll
      for (int j = 0; j < 4; ++j) {
        pfa[j] = (bf16)p0[j]; pfa[4 + j] = (bf16)p1[j];
        pfb[j] = (bf16)p2[j]; pfb[4 + j] = (bf16)p3[j];
      }
      #pragma unroll
      for (int j = 0; j < 4; ++j) {
        const float scj = __shfl(sc, 4*g + j);
        #pragma unroll
        for (int c = 0; c < 4; ++c) ov[c][j] *= scj;
      }
      __builtin_amdgcn_s_setprio(1);
      #pragma unroll
      for (int c = 0; c < 4; ++c) {
        bf16x8 vfa = *(const bf16x8*)(Vb + oV[c]);
        bf16x8 vfb = *(const bf16x8*)(Vb + 2048 + oV[c]);
        ov[c] = mfma32(pfa, vfa, ov[c]);
        ov[c] = mfma32(pfb, vfb, ov[c]);
      }
      __builtin_amdgcn_s_setprio(0);
      __syncthreads();
      cur ^= 1;
    }
    #pragma unroll
    for (int j = 0; j < 4; ++j) {
      const float lj = __shfl(l, 4*g + j);
      const float inv = 1.f / lj;
      const int row = b*SS + q0 + 4*g + j;
      #pragma unroll
      for (int c = 0; c < 4; ++c)
        ctx[(size_t)row * DD + h*HDIM + c*16 + r] = (bf16)(ov[c][j] * inv);
    }
  }
}

// ---------------- LayerNorm(a + p0 [+ p1 + colbias]) * g + b ----------------
template<int NP, int HASB, int WRITEB>
__global__ __launch_bounds__(256)
void ln_kernel(const float* __restrict__ a, const float* __restrict__ p0,
               const float* __restrict__ p1, const float* __restrict__ cb,
               const float* __restrict__ gam, const float* __restrict__ bet,
               float* __restrict__ outf, bf16* __restrict__ outb) {
  const int row = blockIdx.x;
  const int tid = threadIdx.x;
  const size_t base = (size_t)row * DD + tid * 4;
  float4 va = *(const float4*)(a + base);
  float4 vc = *(const float4*)(p0 + base);
  float x0 = va.x + vc.x, x1 = va.y + vc.y, x2 = va.z + vc.z, x3 = va.w + vc.w;
  if (NP > 1) {
    float4 vp = *(const float4*)(p1 + base);
    x0 += vp.x; x1 += vp.y; x2 += vp.z; x3 += vp.w;
  }
  if (HASB) {
    float4 vb4 = *(const float4*)(cb + tid * 4);
    x0 += vb4.x; x1 += vb4.y; x2 += vb4.z; x3 += vb4.w;
  }
  float s  = x0 + x1 + x2 + x3;
  float s2 = x0*x0 + x1*x1 + x2*x2 + x3*x3;
  #pragma unroll
  for (int off = 32; off > 0; off >>= 1) {
    s  += __shfl_xor(s,  off);
    s2 += __shfl_xor(s2, off);
  }
  __shared__ float red[8];
  const int wv = tid >> 6;
  if ((tid & 63) == 0) { red[wv] = s; red[wv + 4] = s2; }
  __syncthreads();
  s  = red[0] + red[1] + red[2] + red[3];
  s2 = red[4] + red[5] + red[6] + red[7];
  const float mu  = s * (1.f / DD);
  const float var = s2 * (1.f / DD) - mu * mu;
  const float rs  = rsqrtf(var + 1e-5f);
  float4 vg = *(const float4*)(gam + tid * 4);
  float4 vb = *(const float4*)(bet + tid * 4);
  float y0 = (x0 - mu) * rs * vg.x + vb.x;
  float y1 = (x1 - mu) * rs * vg.y + vb.y;
  float y2 = (x2 - mu) * rs * vg.z + vb.z;
  float y3 = (x3 - mu) * rs * vg.w + vb.w;
  float4 yo; yo.x = y0; yo.y = y1; yo.z = y2; yo.w = y3;
  *(float4*)(outf + base) = yo;
  if (WRITEB) {
    bf16x4 ob;
    ob[0] = (bf16)y0; ob[1] = (bf16)y1; ob[2] = (bf16)y2; ob[3] = (bf16)y3;
    *(bf16x4*)(outb + base) = ob;
  }
}

// ---------------- LayerNorm(a + sum(4 bf16 partials) + colbias) * g + b ----------------
__global__ __launch_bounds__(256)
void ln_bf4_kernel(const float* __restrict__ a, P4 part, const float* __restrict__ cb,
                   const float* __restrict__ gam, const float* __restrict__ bet,
                   float* __restrict__ outf) {
  const int row = blockIdx.x;
  const int tid = threadIdx.x;
  const size_t base = (size_t)row * DD + tid * 4;
  float4 va = *(const float4*)(a + base);
  bf16x4 u0 = *(const bf16x4*)(part.p[0] + base);
  bf16x4 u1 = *(const bf16x4*)(part.p[1] + base);
  bf16x4 u2 = *(const bf16x4*)(part.p[2] + base);
  bf16x4 u3 = *(const bf16x4*)(part.p[3] + base);
  float4 vb4 = *(const float4*)(cb + tid * 4);
  float x0 = va.x + ((float)u0[0] + (float)u1[0]) + ((float)u2[0] + (float)u3[0]) + vb4.x;
  float x1 = va.y + ((float)u0[1] + (float)u1[1]) + ((float)u2[1] + (float)u3[1]) + vb4.y;
  float x2 = va.z + ((float)u0[2] + (float)u1[2]) + ((float)u2[2] + (float)u3[2]) + vb4.z;
  float x3 = va.w + ((float)u0[3] + (float)u1[3]) + ((float)u2[3] + (float)u3[3]) + vb4.w;
  float s  = x0 + x1 + x2 + x3;
  float s2 = x0*x0 + x1*x1 + x2*x2 + x3*x3;
  #pragma unroll
  for (int off = 32; off > 0; off >>= 1) {
    s  += __shfl_xor(s,  off);
    s2 += __shfl_xor(s2, off);
  }
  __shared__ float red[8];
  const int wv = tid >> 6;
  if ((tid & 63) == 0) { red[wv] = s; red[wv + 4] = s2; }
  __syncthreads();
  s  = red[0] + red[1] + red[2] + red[3];
  s2 = red[4] + red[5] + red[6] + red[7];
  const float mu  = s * (1.f / DD);
  const float var = s2 * (1.f / DD) - mu * mu;
  const float rs  = rsqrtf(var + 1e-5f);
  float4 vg = *(const float4*)(gam + tid * 4);
  float4 vb = *(const float4*)(bet + tid * 4);
  float4 yo;
  yo.x = (x0 - mu) * rs * vg.x + vb.x;
  yo.y = (x1 - mu) * rs * vg.y + vb.y;
  yo.z = (x2 - mu) * rs * vg.z + vb.z;
  yo.w = (x3 - mu) * rs * vg.w + vb.w;
  *(float4*)(outf + base) = yo;
}

extern "C" void kernel_launch(void* const* d_in, const int* in_sizes, int n_in,
                              void* d_out, int out_size, void* d_ws, size_t ws_size,
                              hipStream_t stream) {
  const float* src  = (const float*)d_in[0];
  const float* Wq   = (const float*)d_in[2];
  const float* bq   = (const float*)d_in[3];
  const float* Wk   = (const float*)d_in[4];
  const float* bk   = (const float*)d_in[5];
  const float* Wv   = (const float*)d_in[6];
  const float* bv   = (const float*)d_in[7];
  const float* Wo   = (const float*)d_in[8];
  const float* bo   = (const float*)d_in[9];
  const float* W1   = (const float*)d_in[10];
  const float* b1   = (const float*)d_in[11];
  const float* W2   = (const float*)d_in[12];
  const float* b2   = (const float*)d_in[13];
  const float* ln1g = (const float*)d_in[14];
  const float* ln1b = (const float*)d_in[15];
  const float* ln2g = (const float*)d_in[16];
  const float* ln2b = (const float*)d_in[17];

  char* ws = (char*)d_ws;
  const size_t MB = 1024 * 1024;
  bf16* wqkvt = (bf16*)(ws + 0 * MB);    // 6MB (dead after QKV)
  bf16* wot   = (bf16*)(ws + 6 * MB);    // 2MB (dead after Wo)
  bf16* w1t   = (bf16*)(ws + 8 * MB);    // 8MB (dead after FF1)
  bf16* w2t   = (bf16*)(ws + 16 * MB);   // 8MB (live through FF2)
  bf16* bsrc  = (bf16*)(ws + 24 * MB);   // 8MB; reused as xb (dead after FF1)
  bf16* xb    = bsrc;
  bf16* qkv   = (bf16*)(ws + 32 * MB);   // 24MB (dead after attn)
  bf16* vt    = (bf16*)(ws + 56 * MB);   // 8MB (dead after attn)
  bf16* ctx   = (bf16*)(ws + 64 * MB);   // 8MB (dead after Wo)
  bf16* ff1   = qkv;                     // [4096][4096] = 32MB, reuses qkv+vt
  float* xf   = (float*)(ws + 72 * MB);  // 16MB (live to LN2)
  float* bqkv = (float*)(ws + 88 * MB);  // 12KB
  float* wo_p1 = (float*)(ws + 32 * MB); // 16MB Wo partial over dead qkv (pre-FF1)
  float* attn_out = (float*)d_out;       // Wo partial 0 (fp32) in d_out
  float* outp  = (float*)d_out;
  // FF2 bf16 partials in dead regions at FF2 time
  P4 fp;
  fp.p[0] = (bf16*)(ws + 0 * MB);        // over dead wqkvt
  fp.p[1] = (bf16*)(ws + 8 * MB);        // over dead w1t
  fp.p[2] = (bf16*)(ws + 24 * MB);       // over dead xb
  fp.p[3] = (bf16*)(ws + 64 * MB);       // over dead ctx

  // conversions
  cvt_bf16_kernel<<<(MR * DD) / 1024, 256, 0, stream>>>(src, bsrc, MR * DD);
  transpose_w_kernel<<<dim3(32, 32), 256, 0, stream>>>(Wq, wqkvt,             DD, DD);
  transpose_w_kernel<<<dim3(32, 32), 256, 0, stream>>>(Wk, wqkvt + 1024*1024, DD, DD);
  transpose_w_kernel<<<dim3(32, 32), 256, 0, stream>>>(Wv, wqkvt + 2048*1024, DD, DD);
  transpose_w_kernel<<<dim3(32, 32), 256, 0, stream>>>(Wo, wot, DD, DD);
  transpose_w_kernel<<<dim3(128, 32), 256, 0, stream>>>(W1, w1t, DD, FFD);
  transpose_w_kernel<<<dim3(32, 128), 256, 0, stream>>>(W2, w2t, FFD, DD);
  concat_bias_kernel<<<12, 256, 0, stream>>>(bq, bk, bv, bqkv);

  // fused QKV projection: [4096,1024] @ [1024,3072] -> [4096,3072] (256^2 pipelined)
  gemm256<1, 0, 1><<<dim3(QKVLD / 256, MR / 256), 512, 0, stream>>>(bsrc, wqkvt, bqkv, qkv, P4{}, QKVLD, DD);
  transpose_v_kernel<<<dim3(SS / 32, HDIM / 32, BB * HH), 256, 0, stream>>>(qkv + 2048, vt);

  // attention (Q at col 0, K at col 1024 of qkv)
  attn_kernel<<<dim3(16, BB * HH), 256, 0, stream>>>(qkv, qkv + 1024, vt, ctx);

  // output projection split-K=2 (bias deferred to LN1) + LN1
  gemm_bt<0, 0, 2><<<dim3(8, 32, 2), 256, 0, stream>>>(ctx, wot, nullptr, attn_out, wo_p1, MR, DD, DD);
  ln_kernel<2, 1, 1><<<MR, 256, 0, stream>>>(src, attn_out, wo_p1, bo, ln1g, ln1b, xf, xb);

  // FFN: FF1 256^2 pipelined; FF2 256^2 split-K=4 (bf16 partials), reduce fused in LN2
  gemm256<1, 1, 1><<<dim3(FFD / 256, MR / 256), 512, 0, stream>>>(xb, w1t, b1, ff1, P4{}, FFD, DD);
  gemm256<0, 0, 4><<<dim3(DD / 256, MR / 256, 4), 512, 0, stream>>>(ff1, w2t, nullptr, nullptr, fp, DD, FFD);
  ln_bf4_kernel<<<MR, 256, 0, stream>>>(xf, fp, b2, ln2g, ln2b, outp);
}